// Round 2
// baseline (817.528 us; speedup 1.0000x reference)
//
#include <hip/hip_runtime.h>

// RGATConv x2 (N=50000, E=800000, IN=HID=128, R=8) for MI355X/gfx950.
//
// Round-1 restructure: aggregate-then-transform.
//   out_n = relu(b + [Σ_{e:dst=n} w_e · onehot_r(et_e) ⊗ x_src] @ W_stacked)
// Pipeline per graph:
//   1. Wb = bf16 B-fragment-packed stacked W [32kk,8nt,64lane,8j] (k=r*128+d)
//   2. Wq[r]=W_r@q, Wk[r]=W_r@k (folds attention dots into x-space)
//   3. k_sqk: s_q[n,r], s_k[n,r] + xb=bf16(x)
//   4. CSR by dst: histogram -> scan -> scatter (packed src*8|et)
//   5. k_aggregate: per-dst softmax over in-edges, accumulate w_e*x_src into
//      agg[n, et*128+d] (fp32 regs -> bf16 store, [N,1024])
//   6. k_gemm_out: [N,1024]@[1024,128] MFMA + bias + relu -> fp32 out

typedef unsigned short u16;
typedef __attribute__((ext_vector_type(8))) short short8;
typedef __attribute__((ext_vector_type(4))) float floatx4;

__device__ __forceinline__ u16 f2bf(float f) {
  union { float f; unsigned u; } v; v.f = f;
  unsigned r = v.u + 0x7FFFu + ((v.u >> 16) & 1u);  // RNE
  return (u16)(r >> 16);
}
__device__ __forceinline__ float bf2f(u16 u) {
  union { unsigned u; float f; } v; v.u = ((unsigned)u) << 16; return v.f;
}

// ---- 1. pack stacked W into B-fragment order --------------------------------
// Wb[((kk*8+nt)*64+lane)*8+j] = bf16(Wflat[(kk*32+(lane>>4)*8+j)][nt*16+(lane&15)])
// where Wflat is [R*128, 128] (k = r*128 + d). kk in [0,32).
__global__ void k_prep_wb(const float* __restrict__ W, u16* __restrict__ Wb, int KK) {
  int t = blockIdx.x * 256 + threadIdx.x;
  int lane = t & 63, nt = (t >> 6) & 7, kk = t >> 9;
  if (kk >= KK) return;
  int q = lane >> 4, m16 = lane & 15;
  int c = nt * 16 + m16;
  short8 v;
#pragma unroll
  for (int j = 0; j < 8; ++j) {
    int k = kk * 32 + q * 8 + j;
    v[j] = (short)f2bf(W[(size_t)k * 128 + c]);
  }
  *(short8*)(Wb + (size_t)t * 8) = v;
}

// ---- 2. Wq[r][d] = sum_c W[r][d][c]*q[c]; Wk likewise -----------------------
__global__ void k_prep_wqk(const float* __restrict__ W, const float* __restrict__ qv,
                           const float* __restrict__ kv, float* __restrict__ Wq,
                           float* __restrict__ Wk, int R) {
  int wid = (blockIdx.x * 256 + threadIdx.x) >> 6;
  int lane = threadIdx.x & 63;
  if (wid >= R * 128) return;
  const float* row = W + (size_t)wid * 128;
  float a0 = row[lane], a1 = row[lane + 64];
  float vq = a0 * qv[lane] + a1 * qv[lane + 64];
  float vk = a0 * kv[lane] + a1 * kv[lane + 64];
#pragma unroll
  for (int off = 32; off; off >>= 1) {
    vq += __shfl_xor(vq, off);
    vk += __shfl_xor(vk, off);
  }
  if (lane == 0) { Wq[wid] = vq; Wk[wid] = vk; }
}

// ---- 3. s_q[n][r], s_k[n][r] + bf16 convert of x ----------------------------
__global__ void k_sqk(const float* __restrict__ x, const float* __restrict__ Wq,
                      const float* __restrict__ Wk, float* __restrict__ sq,
                      float* __restrict__ sk, u16* __restrict__ xb, int N) {
  int wid = (blockIdx.x * 256 + threadIdx.x) >> 6;
  int lane = threadIdx.x & 63;
  if (wid >= N) return;
  float x0 = x[(size_t)wid * 128 + lane], x1 = x[(size_t)wid * 128 + 64 + lane];
  xb[(size_t)wid * 128 + lane] = f2bf(x0);
  xb[(size_t)wid * 128 + 64 + lane] = f2bf(x1);
#pragma unroll
  for (int r = 0; r < 8; ++r) {
    float vq = x0 * Wq[r * 128 + lane] + x1 * Wq[r * 128 + 64 + lane];
    float vk = x0 * Wk[r * 128 + lane] + x1 * Wk[r * 128 + 64 + lane];
#pragma unroll
    for (int off = 32; off; off >>= 1) {
      vq += __shfl_xor(vq, off);
      vk += __shfl_xor(vk, off);
    }
    if (lane == 0) { sq[wid * 8 + r] = vq; sk[wid * 8 + r] = vk; }
  }
}

// ---- 4. CSR build -----------------------------------------------------------
__global__ void k_hist(const int* __restrict__ dst, int* __restrict__ cnt, int E) {
  int e = blockIdx.x * 256 + threadIdx.x;
  if (e < E) atomicAdd(&cnt[dst[e]], 1);
}

__global__ void k_scan_block(const int* __restrict__ cnt, int* __restrict__ excl,
                             int* __restrict__ bsum, int n) {
  __shared__ int sd[256];
  int tid = threadIdx.x;
  int base = blockIdx.x * 1024 + tid * 4;
  int v[4]; int tot = 0;
#pragma unroll
  for (int i = 0; i < 4; ++i) {
    int idx = base + i;
    v[i] = (idx < n) ? cnt[idx] : 0;
    tot += v[i];
  }
  sd[tid] = tot; __syncthreads();
  for (int off = 1; off < 256; off <<= 1) {
    int t = (tid >= off) ? sd[tid - off] : 0;
    __syncthreads();
    sd[tid] += t;
    __syncthreads();
  }
  int texcl = sd[tid] - tot;
  if (tid == 255) bsum[blockIdx.x] = sd[255];
  int run = texcl;
#pragma unroll
  for (int i = 0; i < 4; ++i) {
    int idx = base + i;
    if (idx < n) excl[idx] = run;
    run += v[i];
  }
}

__global__ void k_scan_top(int* __restrict__ bsum, int nb) {
  if (blockIdx.x == 0 && threadIdx.x == 0) {
    int run = 0;
    for (int i = 0; i < nb; ++i) { int t = bsum[i]; bsum[i] = run; run += t; }
  }
}

// finalizes offs; re-initializes cnt as the scatter cursor
__global__ void k_scan_add(int* __restrict__ offs, int* __restrict__ cursor,
                           const int* __restrict__ bsum, int n, int total) {
  int i = blockIdx.x * 256 + threadIdx.x;
  if (i < n) {
    int vv = offs[i] + bsum[i >> 10];
    offs[i] = vv; cursor[i] = vv;
  }
  if (i == 0) offs[n] = total;
}

__global__ void k_scatter(const int* __restrict__ src, const int* __restrict__ dst,
                          const int* __restrict__ et, int* __restrict__ cursor,
                          int* __restrict__ csr, int E) {
  int e = blockIdx.x * 256 + threadIdx.x;
  if (e < E) {
    int slot = atomicAdd(&cursor[dst[e]], 1);
    csr[slot] = (src[e] << 3) | et[e];
  }
}

// ---- 5. per-dst softmax + x-space aggregation -------------------------------
__global__ void __launch_bounds__(128) k_aggregate(
    const int* __restrict__ csr, const int* __restrict__ offs,
    const float* __restrict__ sq, const float* __restrict__ sk,
    const u16* __restrict__ xb, u16* __restrict__ agg, int N) {
  __shared__ float red[128];
  __shared__ float wch[128];
  __shared__ int bch[128];
  int n = blockIdx.x, tid = threadIdx.x;
  int start = offs[n], end = offs[n + 1];
  const float* sqn = sq + n * 8;

  // pass 1: segment max of leaky_relu(alpha)
  float m = -INFINITY;
  for (int i = start + tid; i < end; i += 128) {
    int p = csr[i]; int s = p >> 3, e = p & 7;
    float a = sqn[e] + sk[s * 8 + e];
    a = (a > 0.f) ? a : 0.2f * a;
    m = fmaxf(m, a);
  }
  red[tid] = m; __syncthreads();
#pragma unroll
  for (int s = 64; s > 0; s >>= 1) {
    if (tid < s) red[tid] = fmaxf(red[tid], red[tid + s]);
    __syncthreads();
  }
  m = red[0]; __syncthreads();

  // pass 2: sum of exp
  float ssum = 0.f;
  for (int i = start + tid; i < end; i += 128) {
    int p = csr[i]; int s = p >> 3, e = p & 7;
    float a = sqn[e] + sk[s * 8 + e];
    a = (a > 0.f) ? a : 0.2f * a;
    ssum += __expf(a - m);
  }
  red[tid] = ssum; __syncthreads();
#pragma unroll
  for (int s = 64; s > 0; s >>= 1) {
    if (tid < s) red[tid] += red[tid + s];
    __syncthreads();
  }
  float inv = 1.f / (red[0] + 1e-16f); __syncthreads();

  // pass 3: agg[n, r*128+tid] = sum_{e: et=r} w_e * xb[src_e][tid]
  float a0 = 0.f, a1 = 0.f, a2 = 0.f, a3 = 0.f,
        a4 = 0.f, a5 = 0.f, a6 = 0.f, a7 = 0.f;
  for (int base = start; base < end; base += 128) {
    int cntc = min(128, end - base);
    if (tid < cntc) {
      int p = csr[base + tid]; int s = p >> 3, e = p & 7;
      float a = sqn[e] + sk[s * 8 + e];
      a = (a > 0.f) ? a : 0.2f * a;
      wch[tid] = __expf(a - m) * inv;
      bch[tid] = p;
    }
    __syncthreads();
    for (int e2 = 0; e2 < cntc; ++e2) {
      int p = bch[e2];                       // wave-uniform (LDS broadcast)
      float t = wch[e2] * bf2f(xb[(size_t)(p >> 3) * 128 + tid]);
      int r = p & 7;
      if (r == 0) a0 += t;
      else if (r == 1) a1 += t;
      else if (r == 2) a2 += t;
      else if (r == 3) a3 += t;
      else if (r == 4) a4 += t;
      else if (r == 5) a5 += t;
      else if (r == 6) a6 += t;
      else a7 += t;
    }
    __syncthreads();
  }
  u16* ap = agg + (size_t)n * 1024 + tid;
  ap[0]   = f2bf(a0); ap[128] = f2bf(a1); ap[256] = f2bf(a2); ap[384] = f2bf(a3);
  ap[512] = f2bf(a4); ap[640] = f2bf(a5); ap[768] = f2bf(a6); ap[896] = f2bf(a7);
}

// ---- 6. out = relu(agg @ Wstacked + b)  (MFMA bf16, K=1024) -----------------
__global__ void __launch_bounds__(256) k_gemm_out(const u16* __restrict__ agg,
                                                  const u16* __restrict__ Wb,
                                                  const float* __restrict__ bias,
                                                  float* __restrict__ out, int N) {
  int wave = threadIdx.x >> 6, lane = threadIdx.x & 63;
  int m0 = blockIdx.x * 64 + wave * 16;
  int q = lane >> 4, m16 = lane & 15;
  int arow = m0 + m16; if (arow >= N) arow = N - 1;
  floatx4 acc[8];
#pragma unroll
  for (int nt = 0; nt < 8; ++nt) acc[nt] = (floatx4){0.f, 0.f, 0.f, 0.f};
  const u16* ap = agg + (size_t)arow * 1024 + q * 8;
#pragma unroll 4
  for (int kk = 0; kk < 32; ++kk) {
    short8 a = *(const short8*)(ap + kk * 32);
    const u16* wbp = Wb + ((size_t)(kk * 8) * 64 + lane) * 8;
#pragma unroll
    for (int nt = 0; nt < 8; ++nt) {
      short8 b = *(const short8*)(wbp + nt * 512);
      acc[nt] = __builtin_amdgcn_mfma_f32_16x16x32_bf16(a, b, acc[nt], 0, 0, 0);
    }
  }
  // C/D layout: col = nt*16 + (lane&15), row = m0 + (lane>>4)*4 + reg
#pragma unroll
  for (int nt = 0; nt < 8; ++nt) {
    int c = nt * 16 + m16;
    float bc = bias[c];
#pragma unroll
    for (int reg = 0; reg < 4; ++reg) {
      int row = m0 + q * 4 + reg;
      if (row < N) out[(size_t)row * 128 + c] = fmaxf(acc[nt][reg] + bc, 0.f);
    }
  }
}

// -----------------------------------------------------------------------------
extern "C" void kernel_launch(void* const* d_in, const int* in_sizes, int n_in,
                              void* d_out, int out_size, void* d_ws, size_t ws_size,
                              hipStream_t stream) {
  const float* x1 = (const float*)d_in[0];
  const int* ei1 = (const int*)d_in[1];
  const int* et1 = (const int*)d_in[2];
  const float* x2 = (const float*)d_in[3];
  const int* ei2 = (const int*)d_in[4];
  const int* et2 = (const int*)d_in[5];
  const float* W1 = (const float*)d_in[6];
  const float* q1 = (const float*)d_in[7];
  const float* k1 = (const float*)d_in[8];
  const float* b1 = (const float*)d_in[9];
  const float* W2 = (const float*)d_in[10];
  const float* q2 = (const float*)d_in[11];
  const float* k2 = (const float*)d_in[12];
  const float* b2 = (const float*)d_in[13];

  const int N = in_sizes[0] / 128;
  const int E = in_sizes[1] / 2;
  const int R = in_sizes[6] / (128 * 128);
  const int KK = R * 4;  // K/32 for the stacked GEMM

  // workspace carve (256B aligned)
  size_t off = 0;
  char* w = (char*)d_ws;
  auto carve = [&](size_t bytes) -> void* {
    void* p = w + off;
    off += (bytes + 255) & ~(size_t)255;
    return p;
  };
  u16* agg = (u16*)carve((size_t)N * R * 128 * 2);
  u16* xb = (u16*)carve((size_t)N * 128 * 2);
  u16* Wb = (u16*)carve((size_t)KK * 8 * 64 * 8 * 2);
  float* Wq = (float*)carve((size_t)R * 128 * 4);
  float* Wk = (float*)carve((size_t)R * 128 * 4);
  float* sq = (float*)carve((size_t)N * 8 * 4);
  float* sk = (float*)carve((size_t)N * 8 * 4);
  int* cnt = (int*)carve((size_t)(N + 1) * 4);   // reused as scatter cursor
  int* offs = (int*)carve((size_t)(N + 1) * 4);
  int* bsum = (int*)carve(1024 * 4);
  int* csr = (int*)carve((size_t)E * 4);
  if (off > ws_size) return;  // insufficient workspace — fail visibly via absmax

  const int nscan = (N + 1023) / 1024;

  for (int g = 0; g < 2; ++g) {
    const float* x = g ? x2 : x1;
    const int* ei = g ? ei2 : ei1;
    const int* et = g ? et2 : et1;
    const float* W = g ? W2 : W1;
    const float* qv = g ? q2 : q1;
    const float* kv = g ? k2 : k1;
    const float* bv = g ? b2 : b1;
    float* outp = (float*)d_out + (size_t)g * N * 128;

    hipMemsetAsync(cnt, 0, (size_t)(N + 1) * 4, stream);
    k_prep_wb<<<dim3((KK * 512 + 255) / 256), dim3(256), 0, stream>>>(W, Wb, KK);
    k_prep_wqk<<<dim3((R * 128 * 64 + 255) / 256), dim3(256), 0, stream>>>(W, qv, kv, Wq, Wk, R);
    k_sqk<<<dim3((N * 64 + 255) / 256), dim3(256), 0, stream>>>(x, Wq, Wk, sq, sk, xb, N);
    k_hist<<<dim3((E + 255) / 256), dim3(256), 0, stream>>>(ei + E, cnt, E);
    k_scan_block<<<dim3(nscan), dim3(256), 0, stream>>>(cnt, offs, bsum, N);
    k_scan_top<<<dim3(1), dim3(64), 0, stream>>>(bsum, nscan);
    k_scan_add<<<dim3((N + 255) / 256), dim3(256), 0, stream>>>(offs, cnt, bsum, N, E);
    k_scatter<<<dim3((E + 255) / 256), dim3(256), 0, stream>>>(ei, ei + E, et, cnt, csr, E);
    k_aggregate<<<dim3(N), dim3(128), 0, stream>>>(csr, offs, sq, sk, xb, agg, N);
    k_gemm_out<<<dim3((N + 63) / 64), dim3(256), 0, stream>>>(agg, Wb, bv, outp, N);
  }
}

// Round 3
// 598.134 us; speedup vs baseline: 1.3668x; 1.3668x over previous
//
#include <hip/hip_runtime.h>

// RGATConv x2 (N=50000, E=800000, IN=HID=128, R=8) for MI355X/gfx950.
//
// Round-3: transform-then-gather (R1 structure) + latency-tuned aggregate.
//   1. Wb = bf16 B-fragment-packed stacked W [32kk,8nt,64lane,8j]
//   2. Wq[r]=W_r@q, Wk[r]=W_r@k (folds attention dots into x-space)
//   3. k_sqk: s_q[n,r], s_k[n,r] + xb=bf16(x)
//   4. k_gemm_xt: xt[r,n,:] = x_n @ W_r (MFMA, LDS-transposed coalesced stores)
//   5. CSR by dst: histogram -> scan (parallel top) -> scatter (src*8|et)
//   6. k_aggregate: ONE WAVE per dst node; alpha cached in regs; u32/lane row
//      gather with shfl-broadcast (w, rowbase); unroll-4 ILP; NT out store.

typedef unsigned short u16;
typedef __attribute__((ext_vector_type(8))) short short8;
typedef __attribute__((ext_vector_type(4))) float floatx4;

__device__ __forceinline__ u16 f2bf(float f) {
  union { float f; unsigned u; } v; v.f = f;
  unsigned r = v.u + 0x7FFFu + ((v.u >> 16) & 1u);  // RNE
  return (u16)(r >> 16);
}
__device__ __forceinline__ float bf2f(u16 u) {
  union { unsigned u; float f; } v; v.u = ((unsigned)u) << 16; return v.f;
}
__device__ __forceinline__ float bflo(unsigned v) {
  union { unsigned u; float f; } c; c.u = v << 16; return c.f;
}
__device__ __forceinline__ float bfhi(unsigned v) {
  union { unsigned u; float f; } c; c.u = v & 0xffff0000u; return c.f;
}

// ---- 1. pack stacked W into B-fragment order --------------------------------
// Wb[((kk*8+nt)*64+lane)*8+j] = bf16(Wflat[kk*32+(lane>>4)*8+j][nt*16+(lane&15)])
// Wflat is [R*128,128] (k = r*128 + d); kk in [0,KK=4R).
__global__ void k_prep_wb(const float* __restrict__ W, u16* __restrict__ Wb, int KK) {
  int t = blockIdx.x * 256 + threadIdx.x;
  int lane = t & 63, nt = (t >> 6) & 7, kk = t >> 9;
  if (kk >= KK) return;
  int q = lane >> 4, m16 = lane & 15;
  int c = nt * 16 + m16;
  short8 v;
#pragma unroll
  for (int j = 0; j < 8; ++j) {
    int k = kk * 32 + q * 8 + j;
    v[j] = (short)f2bf(W[(size_t)k * 128 + c]);
  }
  *(short8*)(Wb + (size_t)t * 8) = v;
}

// ---- 2. Wq[r][d] = sum_c W[r][d][c]*q[c]; Wk likewise -----------------------
__global__ void k_prep_wqk(const float* __restrict__ W, const float* __restrict__ qv,
                           const float* __restrict__ kv, float* __restrict__ Wq,
                           float* __restrict__ Wk, int R) {
  int wid = (blockIdx.x * 256 + threadIdx.x) >> 6;
  int lane = threadIdx.x & 63;
  if (wid >= R * 128) return;
  const float* row = W + (size_t)wid * 128;
  float a0 = row[lane], a1 = row[lane + 64];
  float vq = a0 * qv[lane] + a1 * qv[lane + 64];
  float vk = a0 * kv[lane] + a1 * kv[lane + 64];
#pragma unroll
  for (int off = 32; off; off >>= 1) {
    vq += __shfl_xor(vq, off);
    vk += __shfl_xor(vk, off);
  }
  if (lane == 0) { Wq[wid] = vq; Wk[wid] = vk; }
}

// ---- 3. s_q[n][r], s_k[n][r] + bf16 convert of x ----------------------------
__global__ void k_sqk(const float* __restrict__ x, const float* __restrict__ Wq,
                      const float* __restrict__ Wk, float* __restrict__ sq,
                      float* __restrict__ sk, u16* __restrict__ xb, int N) {
  int wid = (blockIdx.x * 256 + threadIdx.x) >> 6;
  int lane = threadIdx.x & 63;
  if (wid >= N) return;
  float x0 = x[(size_t)wid * 128 + lane], x1 = x[(size_t)wid * 128 + 64 + lane];
  xb[(size_t)wid * 128 + lane] = f2bf(x0);
  xb[(size_t)wid * 128 + 64 + lane] = f2bf(x1);
#pragma unroll
  for (int r = 0; r < 8; ++r) {
    float vq = x0 * Wq[r * 128 + lane] + x1 * Wq[r * 128 + 64 + lane];
    float vk = x0 * Wk[r * 128 + lane] + x1 * Wk[r * 128 + 64 + lane];
#pragma unroll
    for (int off = 32; off; off >>= 1) {
      vq += __shfl_xor(vq, off);
      vk += __shfl_xor(vk, off);
    }
    if (lane == 0) { sq[wid * 8 + r] = vq; sk[wid * 8 + r] = vk; }
  }
}

// ---- 4. xt[r][n][c] = x_n @ W_r (MFMA) with coalesced LDS epilogue ----------
__global__ void __launch_bounds__(256) k_gemm_xt(const u16* __restrict__ xb,
                                                 const u16* __restrict__ Wb,
                                                 u16* __restrict__ xt, int N) {
  __shared__ u16 st[4][16 * 136];  // stride 136 breaks write-side bank aliasing
  int r = blockIdx.y;
  int wave = threadIdx.x >> 6, lane = threadIdx.x & 63;
  int m0 = blockIdx.x * 64 + wave * 16;
  int q = lane >> 4, m16 = lane & 15;
  int arow = m0 + m16; if (arow >= N) arow = N - 1;
  floatx4 acc[8];
#pragma unroll
  for (int nt = 0; nt < 8; ++nt) acc[nt] = (floatx4){0.f, 0.f, 0.f, 0.f};
#pragma unroll
  for (int kk = 0; kk < 4; ++kk) {
    short8 a = *(const short8*)(xb + (size_t)arow * 128 + kk * 32 + q * 8);
    const u16* wbp = Wb + ((size_t)((r * 4 + kk) * 8) * 64 + lane) * 8;
#pragma unroll
    for (int nt = 0; nt < 8; ++nt) {
      short8 b = *(const short8*)(wbp + nt * 512);
      acc[nt] = __builtin_amdgcn_mfma_f32_16x16x32_bf16(a, b, acc[nt], 0, 0, 0);
    }
  }
  // C/D layout: col = nt*16 + m16, local row = q*4 + reg
  u16* s = st[wave];
#pragma unroll
  for (int nt = 0; nt < 8; ++nt) {
#pragma unroll
    for (int reg = 0; reg < 4; ++reg) {
      s[(q * 4 + reg) * 136 + nt * 16 + m16] = f2bf(acc[nt][reg]);
    }
  }
  __syncthreads();
#pragma unroll
  for (int m = 0; m < 16; ++m) {
    int gm = m0 + m;
    if (gm < N) {
      unsigned vv = *(const unsigned*)(s + m * 136 + lane * 2);
      *(unsigned*)(xt + ((size_t)r * N + gm) * 128 + lane * 2) = vv;
    }
  }
}

// ---- 5. CSR build -----------------------------------------------------------
__global__ void k_hist(const int* __restrict__ dst, int* __restrict__ cnt, int E) {
  int e = blockIdx.x * 256 + threadIdx.x;
  if (e < E) atomicAdd(&cnt[dst[e]], 1);
}

__global__ void k_scan_block(const int* __restrict__ cnt, int* __restrict__ excl,
                             int* __restrict__ bsum, int n) {
  __shared__ int sd[256];
  int tid = threadIdx.x;
  int base = blockIdx.x * 1024 + tid * 4;
  int v[4]; int tot = 0;
#pragma unroll
  for (int i = 0; i < 4; ++i) {
    int idx = base + i;
    v[i] = (idx < n) ? cnt[idx] : 0;
    tot += v[i];
  }
  sd[tid] = tot; __syncthreads();
  for (int off = 1; off < 256; off <<= 1) {
    int t = (tid >= off) ? sd[tid - off] : 0;
    __syncthreads();
    sd[tid] += t;
    __syncthreads();
  }
  int texcl = sd[tid] - tot;
  if (tid == 255) bsum[blockIdx.x] = sd[255];
  int run = texcl;
#pragma unroll
  for (int i = 0; i < 4; ++i) {
    int idx = base + i;
    if (idx < n) excl[idx] = run;
    run += v[i];
  }
}

// parallel exclusive scan of up to-64 block sums (nb=49 here); serial fallback
__global__ void k_scan_top(int* __restrict__ bsum, int nb) {
  int lane = threadIdx.x;
  if (nb <= 64) {
    int v0 = (lane < nb) ? bsum[lane] : 0;
    int v = v0;
#pragma unroll
    for (int off = 1; off < 64; off <<= 1) {
      int t = __shfl_up(v, off);
      if (lane >= off) v += t;
    }
    if (lane < nb) bsum[lane] = v - v0;  // exclusive
  } else if (lane == 0) {
    int run = 0;
    for (int i = 0; i < nb; ++i) { int t = bsum[i]; bsum[i] = run; run += t; }
  }
}

// finalizes offs; re-initializes the scatter cursor
__global__ void k_scan_add(int* __restrict__ offs, int* __restrict__ cursor,
                           const int* __restrict__ bsum, int n, int total) {
  int i = blockIdx.x * 256 + threadIdx.x;
  if (i < n) {
    int vv = offs[i] + bsum[i >> 10];
    offs[i] = vv; cursor[i] = vv;
  }
  if (i == 0) offs[n] = total;
}

__global__ void k_scatter(const int* __restrict__ src, const int* __restrict__ dst,
                          const int* __restrict__ et, int* __restrict__ cursor,
                          int* __restrict__ csr, int E) {
  int e = blockIdx.x * 256 + threadIdx.x;
  if (e < E) {
    int slot = atomicAdd(&cursor[dst[e]], 1);
    csr[slot] = (src[e] << 3) | et[e];
  }
}

// ---- 6. per-dst softmax + weighted aggregation: ONE WAVE per node -----------
__global__ void __launch_bounds__(256) k_aggregate(
    const int* __restrict__ csr, const int* __restrict__ offs,
    const float* __restrict__ sq, const float* __restrict__ sk,
    const u16* __restrict__ xt, const float* __restrict__ bias,
    float* __restrict__ out, int N) {
  int node = blockIdx.x * 4 + (threadIdx.x >> 6);
  int lane = threadIdx.x & 63;
  if (node >= N) return;
  int start = offs[node], end = offs[node + 1];
  const float* sqn = sq + node * 8;

  // pass 1: cache alpha + packed edge in regs (covers deg<=512); wave-max
  float al[8]; int pl[8];
  float m = -INFINITY;
  {
    int c = 0;
    for (int i = start + lane; i < end; i += 64, ++c) {
      int p = csr[i]; int s = p >> 3, e = p & 7;
      float a = sqn[e] + sk[s * 8 + e];
      a = (a > 0.f) ? a : 0.2f * a;
      if (c < 8) { al[c] = a; pl[c] = p; }
      m = fmaxf(m, a);
    }
  }
#pragma unroll
  for (int off = 32; off; off >>= 1) m = fmaxf(m, __shfl_xor(m, off));

  // pass 2: sum of exp (cached alphas; recompute only beyond cache depth)
  float ssum = 0.f;
  {
    int c = 0;
    for (int i = start + lane; i < end; i += 64, ++c) {
      float a;
      if (c < 8) a = al[c];
      else {
        int p = csr[i]; int s = p >> 3, e = p & 7;
        a = sqn[e] + sk[s * 8 + e];
        a = (a > 0.f) ? a : 0.2f * a;
      }
      ssum += __expf(a - m);
    }
  }
#pragma unroll
  for (int off = 32; off; off >>= 1) ssum += __shfl_xor(ssum, off);
  float inv = 1.f / (ssum + 1e-16f);

  // pass 3: lane owns cols {2*lane, 2*lane+1}; per 64-edge chunk each lane
  // prepares (w, rowbase) for edge base+lane, broadcast via shfl; u32 gathers.
  float acc0 = 0.f, acc1 = 0.f;
  const char* xtb = (const char*)xt;
  int c = 0;
  for (int base = start; base < end; base += 64, ++c) {
    int cnt = min(64, end - base);
    float w = 0.f; int b = 0;
    {
      int i = base + lane;
      if (i < end) {
        int p; float a;
        if (c < 8) { p = pl[c]; a = al[c]; }
        else {
          p = csr[i]; int s = p >> 3, e = p & 7;
          a = sqn[e] + sk[s * 8 + e];
          a = (a > 0.f) ? a : 0.2f * a;
        }
        w = __expf(a - m) * inv;
        b = ((p & 7) * N + (p >> 3)) << 8;  // row base in BYTES (128*2B)
      }
    }
    int j = 0;
    for (; j + 3 < cnt; j += 4) {
      float w0 = __shfl(w, j), w1 = __shfl(w, j + 1),
            w2 = __shfl(w, j + 2), w3 = __shfl(w, j + 3);
      int b0 = __shfl(b, j), b1 = __shfl(b, j + 1),
          b2 = __shfl(b, j + 2), b3 = __shfl(b, j + 3);
      unsigned v0 = *(const unsigned*)(xtb + b0 + lane * 4);
      unsigned v1 = *(const unsigned*)(xtb + b1 + lane * 4);
      unsigned v2 = *(const unsigned*)(xtb + b2 + lane * 4);
      unsigned v3 = *(const unsigned*)(xtb + b3 + lane * 4);
      acc0 += w0 * bflo(v0); acc1 += w0 * bfhi(v0);
      acc0 += w1 * bflo(v1); acc1 += w1 * bfhi(v1);
      acc0 += w2 * bflo(v2); acc1 += w2 * bfhi(v2);
      acc0 += w3 * bflo(v3); acc1 += w3 * bfhi(v3);
    }
    for (; j < cnt; ++j) {
      float w0 = __shfl(w, j);
      int b0 = __shfl(b, j);
      unsigned v0 = *(const unsigned*)(xtb + b0 + lane * 4);
      acc0 += w0 * bflo(v0); acc1 += w0 * bfhi(v0);
    }
  }
  float o0 = fmaxf(acc0 + bias[lane * 2], 0.f);
  float o1 = fmaxf(acc1 + bias[lane * 2 + 1], 0.f);
  union { float f[2]; unsigned long long u; } pk;
  pk.f[0] = o0; pk.f[1] = o1;
  __builtin_nontemporal_store(pk.u,
      (unsigned long long*)(out + (size_t)node * 128 + lane * 2));
}

// -----------------------------------------------------------------------------
extern "C" void kernel_launch(void* const* d_in, const int* in_sizes, int n_in,
                              void* d_out, int out_size, void* d_ws, size_t ws_size,
                              hipStream_t stream) {
  const float* x1 = (const float*)d_in[0];
  const int* ei1 = (const int*)d_in[1];
  const int* et1 = (const int*)d_in[2];
  const float* x2 = (const float*)d_in[3];
  const int* ei2 = (const int*)d_in[4];
  const int* et2 = (const int*)d_in[5];
  const float* W1 = (const float*)d_in[6];
  const float* q1 = (const float*)d_in[7];
  const float* k1 = (const float*)d_in[8];
  const float* b1 = (const float*)d_in[9];
  const float* W2 = (const float*)d_in[10];
  const float* q2 = (const float*)d_in[11];
  const float* k2 = (const float*)d_in[12];
  const float* b2 = (const float*)d_in[13];

  const int N = in_sizes[0] / 128;
  const int E = in_sizes[1] / 2;
  const int R = in_sizes[6] / (128 * 128);
  const int KK = R * 4;

  size_t off = 0;
  char* w = (char*)d_ws;
  auto carve = [&](size_t bytes) -> void* {
    void* p = w + off;
    off += (bytes + 255) & ~(size_t)255;
    return p;
  };
  u16* xt = (u16*)carve((size_t)R * N * 128 * 2);
  u16* xb = (u16*)carve((size_t)N * 128 * 2);
  u16* Wb = (u16*)carve((size_t)KK * 8 * 64 * 8 * 2);
  float* Wq = (float*)carve((size_t)R * 128 * 4);
  float* Wk = (float*)carve((size_t)R * 128 * 4);
  float* sq = (float*)carve((size_t)N * 8 * 4);
  float* sk = (float*)carve((size_t)N * 8 * 4);
  int* cnt = (int*)carve((size_t)(N + 1) * 4);   // reused as scatter cursor
  int* offs = (int*)carve((size_t)(N + 1) * 4);
  int* bsum = (int*)carve(1024 * 4);
  int* csr = (int*)carve((size_t)E * 4);
  if (off > ws_size) return;

  const int nscan = (N + 1023) / 1024;

  for (int g = 0; g < 2; ++g) {
    const float* x = g ? x2 : x1;
    const int* ei = g ? ei2 : ei1;
    const int* et = g ? et2 : et1;
    const float* W = g ? W2 : W1;
    const float* qv = g ? q2 : q1;
    const float* kv = g ? k2 : k1;
    const float* bv = g ? b2 : b1;
    float* outp = (float*)d_out + (size_t)g * N * 128;

    hipMemsetAsync(cnt, 0, (size_t)(N + 1) * 4, stream);
    k_prep_wb<<<dim3((KK * 512 + 255) / 256), dim3(256), 0, stream>>>(W, Wb, KK);
    k_prep_wqk<<<dim3((R * 128 * 64 + 255) / 256), dim3(256), 0, stream>>>(W, qv, kv, Wq, Wk, R);
    k_sqk<<<dim3((N * 64 + 255) / 256), dim3(256), 0, stream>>>(x, Wq, Wk, sq, sk, xb, N);
    k_gemm_xt<<<dim3((N + 63) / 64, R), dim3(256), 0, stream>>>(xb, Wb, xt, N);
    k_hist<<<dim3((E + 255) / 256), dim3(256), 0, stream>>>(ei + E, cnt, E);
    k_scan_block<<<dim3(nscan), dim3(256), 0, stream>>>(cnt, offs, bsum, N);
    k_scan_top<<<dim3(1), dim3(64), 0, stream>>>(bsum, nscan);
    k_scan_add<<<dim3((N + 255) / 256), dim3(256), 0, stream>>>(offs, cnt, bsum, N, E);
    k_scatter<<<dim3((E + 255) / 256), dim3(256), 0, stream>>>(ei, ei + E, et, cnt, csr, E);
    k_aggregate<<<dim3((N + 3) / 4), dim3(256), 0, stream>>>(csr, offs, sq, sk, xt, bv, outp, N);
  }
}

// Round 5
// 524.090 us; speedup vs baseline: 1.5599x; 1.1413x over previous
//
#include <hip/hip_runtime.h>

// RGATConv x2 (N=50000, E=800000, IN=HID=128, R=8) for MI355X/gfx950.
//
// Round-5: round-4 structure with the k_aggregate OOB store fixed
// (output row is graph-LOCAL nl; outp already carries the g*N*128 offset).
//   1. Wb  = bf16 B-fragment-packed stacked W per graph [g][4R kk][8nt][64][8]
//   2. Wq[g,r]=W_r@q, Wk[g,r]=W_r@k (folds attention dots into x-space)
//   3. Bqk = B-fragment pack of [Wq|Wk]  (16 cols: 8 sq + 8 sk)
//   4. k_sqk: [sq|sk] = x @ [Wq|Wk] via MFMA (LDS-staged bf16 x)
//   5. CSR over BOTH graphs: hist -> scan -> scatter (packed src*8|et)
//   6. per graph: k_gemm_xt (xt = x @ W_r, fp32->bf16 in-register A), then
//      k_aggregate (one wave per dst: reg-cached softmax, shfl-bcast gather)

typedef unsigned short u16;
typedef __attribute__((ext_vector_type(8))) short short8;
typedef __attribute__((ext_vector_type(4))) float floatx4;
typedef __attribute__((ext_vector_type(4))) float float4v;

__device__ __forceinline__ u16 f2bf(float f) {
  union { float f; unsigned u; } v; v.f = f;
  unsigned r = v.u + 0x7FFFu + ((v.u >> 16) & 1u);  // RNE
  return (u16)(r >> 16);
}
__device__ __forceinline__ float bflo(unsigned v) {
  union { unsigned u; float f; } c; c.u = v << 16; return c.f;
}
__device__ __forceinline__ float bfhi(unsigned v) {
  union { unsigned u; float f; } c; c.u = v & 0xffff0000u; return c.f;
}

// ---- 1. pack stacked W into B-fragment order (per graph) --------------------
// Wb[g][((kk*8+nt)*64+lane)*8+j] = bf16(W_g[kk*32+(lane>>4)*8+j][nt*16+(lane&15)])
__global__ void k_prep_wb(const float* __restrict__ W1, const float* __restrict__ W2,
                          u16* __restrict__ Wb, int KK) {
  int t = blockIdx.x * 256 + threadIdx.x;
  int lane = t & 63, nt = (t >> 6) & 7, kk = t >> 9;
  if (kk >= KK) return;
  const float* W = blockIdx.y ? W2 : W1;
  u16* out = Wb + (size_t)blockIdx.y * KK * 4096;
  int q = lane >> 4, m16 = lane & 15;
  int c = nt * 16 + m16;
  short8 v;
#pragma unroll
  for (int j = 0; j < 8; ++j) {
    int k = kk * 32 + q * 8 + j;
    v[j] = (short)f2bf(W[(size_t)k * 128 + c]);
  }
  *(short8*)(out + (size_t)t * 8) = v;
}

// ---- 2. Wq[g][r][d] = sum_c W[r][d][c]*q[c]; Wk likewise --------------------
__global__ void k_prep_wqk(const float* __restrict__ W1, const float* __restrict__ q1,
                           const float* __restrict__ k1, const float* __restrict__ W2,
                           const float* __restrict__ q2, const float* __restrict__ k2,
                           float* __restrict__ Wq, float* __restrict__ Wk, int RD) {
  int wid = (blockIdx.x * 256 + threadIdx.x) >> 6;
  int lane = threadIdx.x & 63;
  if (wid >= 2 * RD) return;
  int g = wid >= RD;
  const float* W = g ? W2 : W1;
  const float* qv = g ? q2 : q1;
  const float* kv = g ? k2 : k1;
  const float* row = W + (size_t)(wid - g * RD) * 128;
  float a0 = row[lane], a1 = row[lane + 64];
  float vq = a0 * qv[lane] + a1 * qv[lane + 64];
  float vk = a0 * kv[lane] + a1 * kv[lane + 64];
#pragma unroll
  for (int off = 32; off; off >>= 1) {
    vq += __shfl_xor(vq, off);
    vk += __shfl_xor(vk, off);
  }
  if (lane == 0) { Wq[wid] = vq; Wk[wid] = vk; }
}

// ---- 3. Bqk[g][kk][lane][j]: B-fragment of [Wq|Wk] (16 cols) ----------------
__global__ void k_prep_bqk(const float* __restrict__ Wq, const float* __restrict__ Wk,
                           u16* __restrict__ Bqk, int R) {
  int total = 2 * 4 * 64 * 8;
  for (int idx = threadIdx.x; idx < total; idx += 256) {
    int j = idx & 7, lane = (idx >> 3) & 63, kk = (idx >> 9) & 3, g = idx >> 11;
    int k = kk * 32 + ((lane >> 4) & 3) * 8 + j;
    int n = lane & 15;
    float v = (n < 8) ? Wq[(g * R + n) * 128 + k] : Wk[(g * R + (n & 7)) * 128 + k];
    Bqk[idx] = f2bf(v);
  }
}

// ---- 4. [sq|sk] = x @ [Wq|Wk] via MFMA --------------------------------------
__global__ void __launch_bounds__(256) k_sqk(
    const float* __restrict__ x1, const float* __restrict__ x2,
    const u16* __restrict__ Bqk, float* __restrict__ sq, float* __restrict__ sk,
    int N) {
  __shared__ u16 st[64 * 136];
  int g = blockIdx.y;
  const float* x = g ? x2 : x1;
  int row0 = blockIdx.x * 64;  // graph-local
  int t = threadIdx.x;
#pragma unroll
  for (int i = 0; i < 8; ++i) {
    int e = t * 4 + i * 1024;
    int rl = e >> 7, col = e & 127;
    int srow = row0 + rl; if (srow >= N) srow = N - 1;
    float4v v = *(const float4v*)(x + (size_t)srow * 128 + col);
    union { u16 h[4]; unsigned long long u; } pk;
    pk.h[0] = f2bf(v.x); pk.h[1] = f2bf(v.y);
    pk.h[2] = f2bf(v.z); pk.h[3] = f2bf(v.w);
    *(unsigned long long*)(st + rl * 136 + col) = pk.u;
  }
  __syncthreads();
  int wave = t >> 6, lane = t & 63;
  int q = lane >> 4, m16 = lane & 15;
  floatx4 acc = (floatx4){0.f, 0.f, 0.f, 0.f};
#pragma unroll
  for (int kk = 0; kk < 4; ++kk) {
    short8 a = *(const short8*)(st + (wave * 16 + m16) * 136 + kk * 32 + q * 8);
    short8 b = *(const short8*)(Bqk + ((size_t)g * 4 + kk) * 512 + lane * 8);
    acc = __builtin_amdgcn_mfma_f32_16x16x32_bf16(a, b, acc, 0, 0, 0);
  }
  // C layout: col = m16 (0..7 sq, 8..15 sk), local row = q*4+reg
#pragma unroll
  for (int reg = 0; reg < 4; ++reg) {
    int node = row0 + wave * 16 + q * 4 + reg;
    if (node < N) {
      int gn = g * N + node;
      if (m16 < 8) sq[gn * 8 + m16] = acc[reg];
      else sk[gn * 8 + (m16 & 7)] = acc[reg];
    }
  }
}

// ---- 5. CSR build over both graphs ------------------------------------------
__global__ void k_hist(const int* __restrict__ d1, const int* __restrict__ d2,
                       int* __restrict__ cnt, int N, int E) {
  int e = blockIdx.x * 256 + threadIdx.x;
  if (e >= 2 * E) return;
  int g = e >= E;
  int d = g ? d2[e - E] : d1[e];
  atomicAdd(&cnt[g * N + d], 1);
}

__global__ void k_scan_block(const int* __restrict__ cnt, int* __restrict__ excl,
                             int* __restrict__ bsum, int n) {
  __shared__ int sd[256];
  int tid = threadIdx.x;
  int base = blockIdx.x * 1024 + tid * 4;
  int v[4]; int tot = 0;
#pragma unroll
  for (int i = 0; i < 4; ++i) {
    int idx = base + i;
    v[i] = (idx < n) ? cnt[idx] : 0;
    tot += v[i];
  }
  sd[tid] = tot; __syncthreads();
  for (int off = 1; off < 256; off <<= 1) {
    int t = (tid >= off) ? sd[tid - off] : 0;
    __syncthreads();
    sd[tid] += t;
    __syncthreads();
  }
  int texcl = sd[tid] - tot;
  if (tid == 255) bsum[blockIdx.x] = sd[255];
  int run = texcl;
#pragma unroll
  for (int i = 0; i < 4; ++i) {
    int idx = base + i;
    if (idx < n) excl[idx] = run;
    run += v[i];
  }
}

// exclusive scan of up to 256 block sums, one 256-thread block
__global__ void k_scan_top(int* __restrict__ bsum, int nb) {
  __shared__ int sd[256];
  int tid = threadIdx.x;
  int v = (tid < nb) ? bsum[tid] : 0;
  sd[tid] = v; __syncthreads();
  for (int off = 1; off < 256; off <<= 1) {
    int t = (tid >= off) ? sd[tid - off] : 0;
    __syncthreads();
    sd[tid] += t;
    __syncthreads();
  }
  if (tid < nb) bsum[tid] = sd[tid] - v;
}

__global__ void k_scan_add(int* __restrict__ offs, int* __restrict__ cursor,
                           const int* __restrict__ bsum, int n, int total) {
  int i = blockIdx.x * 256 + threadIdx.x;
  if (i < n) {
    int vv = offs[i] + bsum[i >> 10];
    offs[i] = vv; cursor[i] = vv;
  }
  if (i == 0) offs[n] = total;
}

__global__ void k_scatter(const int* __restrict__ ei1, const int* __restrict__ et1,
                          const int* __restrict__ ei2, const int* __restrict__ et2,
                          int* __restrict__ cursor, int* __restrict__ csr,
                          int N, int E) {
  int e = blockIdx.x * 256 + threadIdx.x;
  if (e >= 2 * E) return;
  int g = e >= E;
  int el = e - g * E;
  const int* ei = g ? ei2 : ei1;
  int s = ei[el], d = ei[E + el];
  int et = (g ? et2 : et1)[el];
  int slot = atomicAdd(&cursor[g * N + d], 1);
  csr[slot] = (s << 3) | et;
}

// ---- 6a. xt[r][n][c] = x_n @ W_r (MFMA, in-register fp32->bf16 A) -----------
__global__ void __launch_bounds__(256) k_gemm_xt(const float* __restrict__ x,
                                                 const u16* __restrict__ Wb,
                                                 u16* __restrict__ xt, int N) {
  __shared__ u16 st[4][16 * 136];
  int r = blockIdx.y;
  int wave = threadIdx.x >> 6, lane = threadIdx.x & 63;
  int m0 = blockIdx.x * 64 + wave * 16;
  int q = lane >> 4, m16 = lane & 15;
  int arow = m0 + m16; if (arow >= N) arow = N - 1;
  floatx4 acc[8];
#pragma unroll
  for (int nt = 0; nt < 8; ++nt) acc[nt] = (floatx4){0.f, 0.f, 0.f, 0.f};
#pragma unroll
  for (int kk = 0; kk < 4; ++kk) {
    const float* ap = x + (size_t)arow * 128 + kk * 32 + q * 8;
    float4v f0 = *(const float4v*)ap;
    float4v f1 = *(const float4v*)(ap + 4);
    short8 a;
    a[0] = (short)f2bf(f0.x); a[1] = (short)f2bf(f0.y);
    a[2] = (short)f2bf(f0.z); a[3] = (short)f2bf(f0.w);
    a[4] = (short)f2bf(f1.x); a[5] = (short)f2bf(f1.y);
    a[6] = (short)f2bf(f1.z); a[7] = (short)f2bf(f1.w);
    const u16* wbp = Wb + ((size_t)((r * 4 + kk) * 8) * 64 + lane) * 8;
#pragma unroll
    for (int nt = 0; nt < 8; ++nt) {
      short8 b = *(const short8*)(wbp + nt * 512);
      acc[nt] = __builtin_amdgcn_mfma_f32_16x16x32_bf16(a, b, acc[nt], 0, 0, 0);
    }
  }
  u16* s = st[wave];
#pragma unroll
  for (int nt = 0; nt < 8; ++nt) {
#pragma unroll
    for (int reg = 0; reg < 4; ++reg) {
      s[(q * 4 + reg) * 136 + nt * 16 + m16] = f2bf(acc[nt][reg]);
    }
  }
  __syncthreads();
#pragma unroll
  for (int m = 0; m < 16; ++m) {
    int gm = m0 + m;
    if (gm < N) {
      unsigned vv = *(const unsigned*)(s + m * 136 + lane * 2);
      *(unsigned*)(xt + ((size_t)r * N + gm) * 128 + lane * 2) = vv;
    }
  }
}

// ---- 6b. per-dst softmax + gather: one wave per node ------------------------
__global__ void __launch_bounds__(256) k_aggregate(
    const int* __restrict__ csr, const int* __restrict__ offs,
    const float* __restrict__ sq, const float* __restrict__ sk,
    const u16* __restrict__ xt, const float* __restrict__ bias,
    float* __restrict__ out, int N, int node_base) {
  int nl = blockIdx.x * 4 + (threadIdx.x >> 6);
  int lane = threadIdx.x & 63;
  if (nl >= N) return;
  int node = node_base + nl;  // global node id in [2N) for offs/sq/sk
  int start = offs[node], end = offs[node + 1];
  const float* sqn = sq + (size_t)node * 8;

  float al[8]; int pl[8];
  float m = -INFINITY;
  {
    int c = 0;
    for (int i = start + lane; i < end; i += 64, ++c) {
      int p = csr[i]; int s = p >> 3, e = p & 7;
      float a = sqn[e] + sk[(size_t)(node_base + s) * 8 + e];
      a = (a > 0.f) ? a : 0.2f * a;
      if (c < 8) { al[c] = a; pl[c] = p; }
      m = fmaxf(m, a);
    }
  }
#pragma unroll
  for (int off = 32; off; off >>= 1) m = fmaxf(m, __shfl_xor(m, off));

  float ssum = 0.f;
  {
    int c = 0;
    for (int i = start + lane; i < end; i += 64, ++c) {
      float a;
      if (c < 8) a = al[c];
      else {
        int p = csr[i]; int s = p >> 3, e = p & 7;
        a = sqn[e] + sk[(size_t)(node_base + s) * 8 + e];
        a = (a > 0.f) ? a : 0.2f * a;
      }
      ssum += __expf(a - m);
    }
  }
#pragma unroll
  for (int off = 32; off; off >>= 1) ssum += __shfl_xor(ssum, off);
  float inv = 1.f / (ssum + 1e-16f);

  float acc0 = 0.f, acc1 = 0.f;
  const char* xtb = (const char*)xt;
  int c = 0;
  for (int base = start; base < end; base += 64, ++c) {
    int cnt = min(64, end - base);
    float w = 0.f; int b = 0;
    {
      int i = base + lane;
      if (i < end) {
        int p; float a;
        if (c < 8) { p = pl[c]; a = al[c]; }
        else {
          p = csr[i]; int s = p >> 3, e = p & 7;
          a = sqn[e] + sk[(size_t)(node_base + s) * 8 + e];
          a = (a > 0.f) ? a : 0.2f * a;
        }
        w = __expf(a - m) * inv;
        b = ((p & 7) * N + (p >> 3)) << 8;  // xt row base in BYTES
      }
    }
    int j = 0;
    for (; j + 3 < cnt; j += 4) {
      float w0 = __shfl(w, j), w1 = __shfl(w, j + 1),
            w2 = __shfl(w, j + 2), w3 = __shfl(w, j + 3);
      int b0 = __shfl(b, j), b1 = __shfl(b, j + 1),
          b2 = __shfl(b, j + 2), b3 = __shfl(b, j + 3);
      unsigned v0 = *(const unsigned*)(xtb + b0 + lane * 4);
      unsigned v1 = *(const unsigned*)(xtb + b1 + lane * 4);
      unsigned v2 = *(const unsigned*)(xtb + b2 + lane * 4);
      unsigned v3 = *(const unsigned*)(xtb + b3 + lane * 4);
      acc0 += w0 * bflo(v0); acc1 += w0 * bfhi(v0);
      acc0 += w1 * bflo(v1); acc1 += w1 * bfhi(v1);
      acc0 += w2 * bflo(v2); acc1 += w2 * bfhi(v2);
      acc0 += w3 * bflo(v3); acc1 += w3 * bfhi(v3);
    }
    for (; j < cnt; ++j) {
      float w0 = __shfl(w, j);
      int b0 = __shfl(b, j);
      unsigned v0 = *(const unsigned*)(xtb + b0 + lane * 4);
      acc0 += w0 * bflo(v0); acc1 += w0 * bfhi(v0);
    }
  }
  float o0 = fmaxf(acc0 + bias[lane * 2], 0.f);
  float o1 = fmaxf(acc1 + bias[lane * 2 + 1], 0.f);
  union { float f[2]; unsigned long long u; } pk;
  pk.f[0] = o0; pk.f[1] = o1;
  // FIX: graph-LOCAL row index (out already offset by g*N*128 at launch)
  __builtin_nontemporal_store(pk.u,
      (unsigned long long*)(out + (size_t)nl * 128 + lane * 2));
}

// -----------------------------------------------------------------------------
extern "C" void kernel_launch(void* const* d_in, const int* in_sizes, int n_in,
                              void* d_out, int out_size, void* d_ws, size_t ws_size,
                              hipStream_t stream) {
  const float* x1 = (const float*)d_in[0];
  const int* ei1 = (const int*)d_in[1];
  const int* et1 = (const int*)d_in[2];
  const float* x2 = (const float*)d_in[3];
  const int* ei2 = (const int*)d_in[4];
  const int* et2 = (const int*)d_in[5];
  const float* W1 = (const float*)d_in[6];
  const float* q1 = (const float*)d_in[7];
  const float* k1 = (const float*)d_in[8];
  const float* b1 = (const float*)d_in[9];
  const float* W2 = (const float*)d_in[10];
  const float* q2 = (const float*)d_in[11];
  const float* k2 = (const float*)d_in[12];
  const float* b2 = (const float*)d_in[13];

  const int N = in_sizes[0] / 128;
  const int E = in_sizes[1] / 2;
  const int R = in_sizes[6] / (128 * 128);
  const int KK = R * 4;
  const int N2 = 2 * N;

  size_t off = 0;
  char* w = (char*)d_ws;
  auto carve = [&](size_t bytes) -> void* {
    void* p = w + off;
    off += (bytes + 255) & ~(size_t)255;
    return p;
  };
  u16* xt = (u16*)carve((size_t)R * N * 128 * 2);       // per-graph, reused
  u16* Wb = (u16*)carve((size_t)2 * KK * 4096 * 2);
  u16* Bqk = (u16*)carve((size_t)2 * 4 * 64 * 8 * 2);
  float* Wq = (float*)carve((size_t)2 * R * 128 * 4);
  float* Wk = (float*)carve((size_t)2 * R * 128 * 4);
  float* sq = (float*)carve((size_t)N2 * 8 * 4);
  float* sk = (float*)carve((size_t)N2 * 8 * 4);
  int* cnt = (int*)carve((size_t)(N2 + 1) * 4);         // reused as cursor
  int* offs = (int*)carve((size_t)(N2 + 1) * 4);
  int* bsum = (int*)carve(1024 * 4);
  int* csr = (int*)carve((size_t)2 * E * 4);
  if (off > ws_size) return;

  const int nscan = (N2 + 1023) / 1024;

  hipMemsetAsync(cnt, 0, (size_t)N2 * 4, stream);
  k_prep_wb<<<dim3((KK * 512 + 255) / 256, 2), dim3(256), 0, stream>>>(W1, W2, Wb, KK);
  k_prep_wqk<<<dim3((2 * R * 128 * 64 + 255) / 256), dim3(256), 0, stream>>>(
      W1, q1, k1, W2, q2, k2, Wq, Wk, R * 128);
  k_prep_bqk<<<dim3(1), dim3(256), 0, stream>>>(Wq, Wk, Bqk, R);
  k_sqk<<<dim3((N + 63) / 64, 2), dim3(256), 0, stream>>>(x1, x2, Bqk, sq, sk, N);
  k_hist<<<dim3((2 * E + 255) / 256), dim3(256), 0, stream>>>(ei1 + E, ei2 + E, cnt, N, E);
  k_scan_block<<<dim3(nscan), dim3(256), 0, stream>>>(cnt, offs, bsum, N2);
  k_scan_top<<<dim3(1), dim3(256), 0, stream>>>(bsum, nscan);
  k_scan_add<<<dim3((N2 + 255) / 256), dim3(256), 0, stream>>>(offs, cnt, bsum, N2, 2 * E);
  k_scatter<<<dim3((2 * E + 255) / 256), dim3(256), 0, stream>>>(ei1, et1, ei2, et2, cnt, csr, N, E);

  for (int g = 0; g < 2; ++g) {
    const float* x = g ? x2 : x1;
    const float* bv = g ? b2 : b1;
    float* outp = (float*)d_out + (size_t)g * N * 128;
    k_gemm_xt<<<dim3((N + 63) / 64, R), dim3(256), 0, stream>>>(
        x, Wb + (size_t)g * KK * 4096, xt, N);
    k_aggregate<<<dim3((N + 3) / 4), dim3(256), 0, stream>>>(
        csr, offs, sq, sk, xt, bv, outp, N, g * N);
  }
}

// Round 6
// 455.122 us; speedup vs baseline: 1.7963x; 1.1515x over previous
//
#include <hip/hip_runtime.h>

// RGATConv x2 (N=50000, E=800000, IN=HID=128, R=8) for MI355X/gfx950.
//
// Round-6: replace atomic scatter (107MB write-amplified, 117us) with a
// two-pass binned scatter:
//   k_bin:      per-block counting-sort into 256-node buckets, coalesced run
//               writes into `staged` (slot space == final csr space).
//   k_scatter2: one block per bucket, LDS cursors, stores confined to the
//               bucket's ~16KB csr window (single-owner lines).
// staged aliases xt (dead until k_gemm_xt, which runs after scatter2).
// Rest identical to round-5.

typedef unsigned short u16;
typedef __attribute__((ext_vector_type(8))) short short8;
typedef __attribute__((ext_vector_type(4))) float floatx4;
typedef __attribute__((ext_vector_type(4))) float float4v;

__device__ __forceinline__ u16 f2bf(float f) {
  union { float f; unsigned u; } v; v.f = f;
  unsigned r = v.u + 0x7FFFu + ((v.u >> 16) & 1u);  // RNE
  return (u16)(r >> 16);
}
__device__ __forceinline__ float bflo(unsigned v) {
  union { unsigned u; float f; } c; c.u = v << 16; return c.f;
}
__device__ __forceinline__ float bfhi(unsigned v) {
  union { unsigned u; float f; } c; c.u = v & 0xffff0000u; return c.f;
}

// ---- 1. pack stacked W into B-fragment order (per graph) --------------------
__global__ void k_prep_wb(const float* __restrict__ W1, const float* __restrict__ W2,
                          u16* __restrict__ Wb, int KK) {
  int t = blockIdx.x * 256 + threadIdx.x;
  int lane = t & 63, nt = (t >> 6) & 7, kk = t >> 9;
  if (kk >= KK) return;
  const float* W = blockIdx.y ? W2 : W1;
  u16* out = Wb + (size_t)blockIdx.y * KK * 4096;
  int q = lane >> 4, m16 = lane & 15;
  int c = nt * 16 + m16;
  short8 v;
#pragma unroll
  for (int j = 0; j < 8; ++j) {
    int k = kk * 32 + q * 8 + j;
    v[j] = (short)f2bf(W[(size_t)k * 128 + c]);
  }
  *(short8*)(out + (size_t)t * 8) = v;
}

// ---- 2. Wq[g][r][d] = sum_c W[r][d][c]*q[c]; Wk likewise --------------------
__global__ void k_prep_wqk(const float* __restrict__ W1, const float* __restrict__ q1,
                           const float* __restrict__ k1, const float* __restrict__ W2,
                           const float* __restrict__ q2, const float* __restrict__ k2,
                           float* __restrict__ Wq, float* __restrict__ Wk, int RD) {
  int wid = (blockIdx.x * 256 + threadIdx.x) >> 6;
  int lane = threadIdx.x & 63;
  if (wid >= 2 * RD) return;
  int g = wid >= RD;
  const float* W = g ? W2 : W1;
  const float* qv = g ? q2 : q1;
  const float* kv = g ? k2 : k1;
  const float* row = W + (size_t)(wid - g * RD) * 128;
  float a0 = row[lane], a1 = row[lane + 64];
  float vq = a0 * qv[lane] + a1 * qv[lane + 64];
  float vk = a0 * kv[lane] + a1 * kv[lane + 64];
#pragma unroll
  for (int off = 32; off; off >>= 1) {
    vq += __shfl_xor(vq, off);
    vk += __shfl_xor(vk, off);
  }
  if (lane == 0) { Wq[wid] = vq; Wk[wid] = vk; }
}

// ---- 3. Bqk[g][kk][lane][j]: B-fragment of [Wq|Wk] (16 cols) ----------------
__global__ void k_prep_bqk(const float* __restrict__ Wq, const float* __restrict__ Wk,
                           u16* __restrict__ Bqk, int R) {
  int total = 2 * 4 * 64 * 8;
  for (int idx = threadIdx.x; idx < total; idx += 256) {
    int j = idx & 7, lane = (idx >> 3) & 63, kk = (idx >> 9) & 3, g = idx >> 11;
    int k = kk * 32 + ((lane >> 4) & 3) * 8 + j;
    int n = lane & 15;
    float v = (n < 8) ? Wq[(g * R + n) * 128 + k] : Wk[(g * R + (n & 7)) * 128 + k];
    Bqk[idx] = f2bf(v);
  }
}

// ---- 4. [sq|sk] = x @ [Wq|Wk] via MFMA --------------------------------------
__global__ void __launch_bounds__(256) k_sqk(
    const float* __restrict__ x1, const float* __restrict__ x2,
    const u16* __restrict__ Bqk, float* __restrict__ sq, float* __restrict__ sk,
    int N) {
  __shared__ u16 st[64 * 136];
  int g = blockIdx.y;
  const float* x = g ? x2 : x1;
  int row0 = blockIdx.x * 64;
  int t = threadIdx.x;
#pragma unroll
  for (int i = 0; i < 8; ++i) {
    int e = t * 4 + i * 1024;
    int rl = e >> 7, col = e & 127;
    int srow = row0 + rl; if (srow >= N) srow = N - 1;
    float4v v = *(const float4v*)(x + (size_t)srow * 128 + col);
    union { u16 h[4]; unsigned long long u; } pk;
    pk.h[0] = f2bf(v.x); pk.h[1] = f2bf(v.y);
    pk.h[2] = f2bf(v.z); pk.h[3] = f2bf(v.w);
    *(unsigned long long*)(st + rl * 136 + col) = pk.u;
  }
  __syncthreads();
  int wave = t >> 6, lane = t & 63;
  int q = lane >> 4, m16 = lane & 15;
  floatx4 acc = (floatx4){0.f, 0.f, 0.f, 0.f};
#pragma unroll
  for (int kk = 0; kk < 4; ++kk) {
    short8 a = *(const short8*)(st + (wave * 16 + m16) * 136 + kk * 32 + q * 8);
    short8 b = *(const short8*)(Bqk + ((size_t)g * 4 + kk) * 512 + lane * 8);
    acc = __builtin_amdgcn_mfma_f32_16x16x32_bf16(a, b, acc, 0, 0, 0);
  }
#pragma unroll
  for (int reg = 0; reg < 4; ++reg) {
    int node = row0 + wave * 16 + q * 4 + reg;
    if (node < N) {
      int gn = g * N + node;
      if (m16 < 8) sq[gn * 8 + m16] = acc[reg];
      else sk[gn * 8 + (m16 & 7)] = acc[reg];
    }
  }
}

// ---- 5. CSR build over both graphs ------------------------------------------
__global__ void k_hist(const int* __restrict__ d1, const int* __restrict__ d2,
                       int* __restrict__ cnt, int N, int E) {
  int e = blockIdx.x * 256 + threadIdx.x;
  if (e >= 2 * E) return;
  int g = e >= E;
  int d = g ? d2[e - E] : d1[e];
  atomicAdd(&cnt[g * N + d], 1);
}

__global__ void k_scan_block(const int* __restrict__ cnt, int* __restrict__ excl,
                             int* __restrict__ bsum, int n) {
  __shared__ int sd[256];
  int tid = threadIdx.x;
  int base = blockIdx.x * 1024 + tid * 4;
  int v[4]; int tot = 0;
#pragma unroll
  for (int i = 0; i < 4; ++i) {
    int idx = base + i;
    v[i] = (idx < n) ? cnt[idx] : 0;
    tot += v[i];
  }
  sd[tid] = tot; __syncthreads();
  for (int off = 1; off < 256; off <<= 1) {
    int t = (tid >= off) ? sd[tid - off] : 0;
    __syncthreads();
    sd[tid] += t;
    __syncthreads();
  }
  int texcl = sd[tid] - tot;
  if (tid == 255) bsum[blockIdx.x] = sd[255];
  int run = texcl;
#pragma unroll
  for (int i = 0; i < 4; ++i) {
    int idx = base + i;
    if (idx < n) excl[idx] = run;
    run += v[i];
  }
}

__global__ void k_scan_top(int* __restrict__ bsum, int nb) {
  __shared__ int sd[256];
  int tid = threadIdx.x;
  int v = (tid < nb) ? bsum[tid] : 0;
  sd[tid] = v; __syncthreads();
  for (int off = 1; off < 256; off <<= 1) {
    int t = (tid >= off) ? sd[tid - off] : 0;
    __syncthreads();
    sd[tid] += t;
    __syncthreads();
  }
  if (tid < nb) bsum[tid] = sd[tid] - v;
}

__global__ void k_scan_add(int* __restrict__ offs, const int* __restrict__ bsum,
                           int n, int total) {
  int i = blockIdx.x * 256 + threadIdx.x;
  if (i < n) offs[i] += bsum[i >> 10];
  if (i == 0) offs[n] = total;
}

// bucketCursor[b] = offs[b*256]  (csr slot base of bucket b)
__global__ void k_binit(const int* __restrict__ offs, int* __restrict__ bcur, int NB) {
  int b = blockIdx.x * 256 + threadIdx.x;
  if (b < NB) bcur[b] = offs[b << 8];
}

// ---- 5a. bin edges into 256-node buckets (counting-sort per 4096-edge chunk)
__global__ void __launch_bounds__(256) k_bin(
    const int* __restrict__ ei1, const int* __restrict__ et1,
    const int* __restrict__ ei2, const int* __restrict__ et2,
    int* __restrict__ bcur, uint2* __restrict__ staged, int N, int E, int NB) {
  __shared__ int hist[512];
  __shared__ int basev[512];
  __shared__ int runstart[512];
  __shared__ unsigned sta[4096 * 2];  // 32 KB staging (dstg, srcet)
  int tid = threadIdx.x;
  int E2 = 2 * E;
  int e0 = blockIdx.x * 4096;
  int cnt2 = min(4096, E2 - e0);
  for (int i = tid; i < 512; i += 256) hist[i] = 0;
  __syncthreads();
  int dstg[16], srcet[16], rank[16];
#pragma unroll
  for (int j = 0; j < 16; ++j) {
    int e = e0 + j * 256 + tid;
    dstg[j] = -1;
    if (e < E2) {
      int g = e >= E;
      int el = e - (g ? E : 0);
      const int* ei = g ? ei2 : ei1;
      int s = ei[el], d = ei[E + el];
      int etv = (g ? et2 : et1)[el];
      dstg[j] = g * N + d;
      srcet[j] = (s << 3) | etv;
      rank[j] = atomicAdd(&hist[dstg[j] >> 8], 1);
    }
  }
  __syncthreads();
  // inclusive Hillis-Steele scan of hist[0..512) into basev (2 elems/thread)
  basev[tid] = hist[tid];
  basev[tid + 256] = hist[tid + 256];
  __syncthreads();
  for (int off = 1; off < 512; off <<= 1) {
    int i0 = tid, i1 = tid + 256;
    int v0 = (i0 >= off) ? basev[i0 - off] : 0;
    int v1 = (i1 >= off) ? basev[i1 - off] : 0;
    __syncthreads();
    basev[i0] += v0; basev[i1] += v1;
    __syncthreads();
  }
  // reserve contiguous global runs (one atomic per non-empty bucket)
  for (int i = tid; i < NB; i += 256)
    if (hist[i] > 0) runstart[i] = atomicAdd(&bcur[i], hist[i]);
  __syncthreads();
  // place into LDS staging, bucket-sorted
#pragma unroll
  for (int j = 0; j < 16; ++j)
    if (dstg[j] >= 0) {
      int b = dstg[j] >> 8;
      int slot = basev[b] - hist[b] + rank[j];
      sta[slot * 2] = (unsigned)dstg[j];
      sta[slot * 2 + 1] = (unsigned)srcet[j];
    }
  __syncthreads();
  // coalesced run writes to staged (global slot space == csr slot space)
  for (int i = tid; i < cnt2; i += 256) {
    unsigned dg = sta[i * 2], se = sta[i * 2 + 1];
    int b = (int)(dg >> 8);
    int dest = runstart[b] + (i - (basev[b] - hist[b]));
    staged[dest] = make_uint2(dg, se);
  }
}

// ---- 5b. final scatter: one block per bucket, LDS cursors, 16KB window ------
__global__ void __launch_bounds__(256) k_scatter2(
    const uint2* __restrict__ staged, const int* __restrict__ offs,
    int* __restrict__ csr, int N2) {
  __shared__ int cur[256];
  int b = blockIdx.x, tid = threadIdx.x;
  int nb0 = b << 8;
  int hi = min(nb0 + 256, N2);
  int s0 = offs[nb0];
  int s1 = offs[hi];
  if (nb0 + tid < hi) cur[tid] = offs[nb0 + tid] - s0;
  __syncthreads();
  for (int i = s0 + tid; i < s1; i += 256) {
    uint2 en = staged[i];
    int node = (int)en.x - nb0;
    int sl = atomicAdd(&cur[node], 1);
    csr[s0 + sl] = (int)en.y;
  }
}

// ---- 6a. xt[r][n][c] = x_n @ W_r (MFMA, in-register fp32->bf16 A) -----------
__global__ void __launch_bounds__(256) k_gemm_xt(const float* __restrict__ x,
                                                 const u16* __restrict__ Wb,
                                                 u16* __restrict__ xt, int N) {
  __shared__ u16 st[4][16 * 136];
  int r = blockIdx.y;
  int wave = threadIdx.x >> 6, lane = threadIdx.x & 63;
  int m0 = blockIdx.x * 64 + wave * 16;
  int q = lane >> 4, m16 = lane & 15;
  int arow = m0 + m16; if (arow >= N) arow = N - 1;
  floatx4 acc[8];
#pragma unroll
  for (int nt = 0; nt < 8; ++nt) acc[nt] = (floatx4){0.f, 0.f, 0.f, 0.f};
#pragma unroll
  for (int kk = 0; kk < 4; ++kk) {
    const float* ap = x + (size_t)arow * 128 + kk * 32 + q * 8;
    float4v f0 = *(const float4v*)ap;
    float4v f1 = *(const float4v*)(ap + 4);
    short8 a;
    a[0] = (short)f2bf(f0.x); a[1] = (short)f2bf(f0.y);
    a[2] = (short)f2bf(f0.z); a[3] = (short)f2bf(f0.w);
    a[4] = (short)f2bf(f1.x); a[5] = (short)f2bf(f1.y);
    a[6] = (short)f2bf(f1.z); a[7] = (short)f2bf(f1.w);
    const u16* wbp = Wb + ((size_t)((r * 4 + kk) * 8) * 64 + lane) * 8;
#pragma unroll
    for (int nt = 0; nt < 8; ++nt) {
      short8 b = *(const short8*)(wbp + nt * 512);
      acc[nt] = __builtin_amdgcn_mfma_f32_16x16x32_bf16(a, b, acc[nt], 0, 0, 0);
    }
  }
  u16* s = st[wave];
#pragma unroll
  for (int nt = 0; nt < 8; ++nt) {
#pragma unroll
    for (int reg = 0; reg < 4; ++reg) {
      s[(q * 4 + reg) * 136 + nt * 16 + m16] = f2bf(acc[nt][reg]);
    }
  }
  __syncthreads();
#pragma unroll
  for (int m = 0; m < 16; ++m) {
    int gm = m0 + m;
    if (gm < N) {
      unsigned vv = *(const unsigned*)(s + m * 136 + lane * 2);
      *(unsigned*)(xt + ((size_t)r * N + gm) * 128 + lane * 2) = vv;
    }
  }
}

// ---- 6b. per-dst softmax + gather: one wave per node ------------------------
__global__ void __launch_bounds__(256) k_aggregate(
    const int* __restrict__ csr, const int* __restrict__ offs,
    const float* __restrict__ sq, const float* __restrict__ sk,
    const u16* __restrict__ xt, const float* __restrict__ bias,
    float* __restrict__ out, int N, int node_base) {
  int nl = blockIdx.x * 4 + (threadIdx.x >> 6);
  int lane = threadIdx.x & 63;
  if (nl >= N) return;
  int node = node_base + nl;
  int start = offs[node], end = offs[node + 1];
  const float* sqn = sq + (size_t)node * 8;

  float al[8]; int pl[8];
  float m = -INFINITY;
  {
    int c = 0;
    for (int i = start + lane; i < end; i += 64, ++c) {
      int p = csr[i]; int s = p >> 3, e = p & 7;
      float a = sqn[e] + sk[(size_t)(node_base + s) * 8 + e];
      a = (a > 0.f) ? a : 0.2f * a;
      if (c < 8) { al[c] = a; pl[c] = p; }
      m = fmaxf(m, a);
    }
  }
#pragma unroll
  for (int off = 32; off; off >>= 1) m = fmaxf(m, __shfl_xor(m, off));

  float ssum = 0.f;
  {
    int c = 0;
    for (int i = start + lane; i < end; i += 64, ++c) {
      float a;
      if (c < 8) a = al[c];
      else {
        int p = csr[i]; int s = p >> 3, e = p & 7;
        a = sqn[e] + sk[(size_t)(node_base + s) * 8 + e];
        a = (a > 0.f) ? a : 0.2f * a;
      }
      ssum += __expf(a - m);
    }
  }
#pragma unroll
  for (int off = 32; off; off >>= 1) ssum += __shfl_xor(ssum, off);
  float inv = 1.f / (ssum + 1e-16f);

  float acc0 = 0.f, acc1 = 0.f;
  const char* xtb = (const char*)xt;
  int c = 0;
  for (int base = start; base < end; base += 64, ++c) {
    int cnt = min(64, end - base);
    float w = 0.f; int b = 0;
    {
      int i = base + lane;
      if (i < end) {
        int p; float a;
        if (c < 8) { p = pl[c]; a = al[c]; }
        else {
          p = csr[i]; int s = p >> 3, e = p & 7;
          a = sqn[e] + sk[(size_t)(node_base + s) * 8 + e];
          a = (a > 0.f) ? a : 0.2f * a;
        }
        w = __expf(a - m) * inv;
        b = ((p & 7) * N + (p >> 3)) << 8;  // xt row base in BYTES
      }
    }
    int j = 0;
    for (; j + 3 < cnt; j += 4) {
      float w0 = __shfl(w, j), w1 = __shfl(w, j + 1),
            w2 = __shfl(w, j + 2), w3 = __shfl(w, j + 3);
      int b0 = __shfl(b, j), b1 = __shfl(b, j + 1),
          b2 = __shfl(b, j + 2), b3 = __shfl(b, j + 3);
      unsigned v0 = *(const unsigned*)(xtb + b0 + lane * 4);
      unsigned v1 = *(const unsigned*)(xtb + b1 + lane * 4);
      unsigned v2 = *(const unsigned*)(xtb + b2 + lane * 4);
      unsigned v3 = *(const unsigned*)(xtb + b3 + lane * 4);
      acc0 += w0 * bflo(v0); acc1 += w0 * bfhi(v0);
      acc0 += w1 * bflo(v1); acc1 += w1 * bfhi(v1);
      acc0 += w2 * bflo(v2); acc1 += w2 * bfhi(v2);
      acc0 += w3 * bflo(v3); acc1 += w3 * bfhi(v3);
    }
    for (; j < cnt; ++j) {
      float w0 = __shfl(w, j);
      int b0 = __shfl(b, j);
      unsigned v0 = *(const unsigned*)(xtb + b0 + lane * 4);
      acc0 += w0 * bflo(v0); acc1 += w0 * bfhi(v0);
    }
  }
  float o0 = fmaxf(acc0 + bias[lane * 2], 0.f);
  float o1 = fmaxf(acc1 + bias[lane * 2 + 1], 0.f);
  union { float f[2]; unsigned long long u; } pk;
  pk.f[0] = o0; pk.f[1] = o1;
  __builtin_nontemporal_store(pk.u,
      (unsigned long long*)(out + (size_t)nl * 128 + lane * 2));
}

// -----------------------------------------------------------------------------
extern "C" void kernel_launch(void* const* d_in, const int* in_sizes, int n_in,
                              void* d_out, int out_size, void* d_ws, size_t ws_size,
                              hipStream_t stream) {
  const float* x1 = (const float*)d_in[0];
  const int* ei1 = (const int*)d_in[1];
  const int* et1 = (const int*)d_in[2];
  const float* x2 = (const float*)d_in[3];
  const int* ei2 = (const int*)d_in[4];
  const int* et2 = (const int*)d_in[5];
  const float* W1 = (const float*)d_in[6];
  const float* q1 = (const float*)d_in[7];
  const float* k1 = (const float*)d_in[8];
  const float* b1 = (const float*)d_in[9];
  const float* W2 = (const float*)d_in[10];
  const float* q2 = (const float*)d_in[11];
  const float* k2 = (const float*)d_in[12];
  const float* b2 = (const float*)d_in[13];

  const int N = in_sizes[0] / 128;
  const int E = in_sizes[1] / 2;
  const int R = in_sizes[6] / (128 * 128);
  const int KK = R * 4;
  const int N2 = 2 * N;
  const int NB = (N2 + 255) >> 8;           // 256-node buckets

  size_t off = 0;
  char* w = (char*)d_ws;
  auto carve = [&](size_t bytes) -> void* {
    void* p = w + off;
    off += (bytes + 255) & ~(size_t)255;
    return p;
  };
  u16* xt = (u16*)carve((size_t)R * N * 128 * 2);       // per-graph, reused
  uint2* staged = (uint2*)xt;                           // ALIAS: dead before gemm_xt
  u16* Wb = (u16*)carve((size_t)2 * KK * 4096 * 2);
  u16* Bqk = (u16*)carve((size_t)2 * 4 * 64 * 8 * 2);
  float* Wq = (float*)carve((size_t)2 * R * 128 * 4);
  float* Wk = (float*)carve((size_t)2 * R * 128 * 4);
  float* sq = (float*)carve((size_t)N2 * 8 * 4);
  float* sk = (float*)carve((size_t)N2 * 8 * 4);
  int* cnt = (int*)carve((size_t)(N2 + 1) * 4);
  int* offs = (int*)carve((size_t)(N2 + 1) * 4);
  int* bsum = (int*)carve(1024 * 4);
  int* bcur = (int*)carve(512 * 4);
  int* csr = (int*)carve((size_t)2 * E * 4);
  if (off > ws_size) return;

  const int nscan = (N2 + 1023) / 1024;
  const int nbin = (2 * E + 4095) / 4096;

  hipMemsetAsync(cnt, 0, (size_t)N2 * 4, stream);
  k_prep_wb<<<dim3((KK * 512 + 255) / 256, 2), dim3(256), 0, stream>>>(W1, W2, Wb, KK);
  k_prep_wqk<<<dim3((2 * R * 128 * 64 + 255) / 256), dim3(256), 0, stream>>>(
      W1, q1, k1, W2, q2, k2, Wq, Wk, R * 128);
  k_prep_bqk<<<dim3(1), dim3(256), 0, stream>>>(Wq, Wk, Bqk, R);
  k_sqk<<<dim3((N + 63) / 64, 2), dim3(256), 0, stream>>>(x1, x2, Bqk, sq, sk, N);
  k_hist<<<dim3((2 * E + 255) / 256), dim3(256), 0, stream>>>(ei1 + E, ei2 + E, cnt, N, E);
  k_scan_block<<<dim3(nscan), dim3(256), 0, stream>>>(cnt, offs, bsum, N2);
  k_scan_top<<<dim3(1), dim3(256), 0, stream>>>(bsum, nscan);
  k_scan_add<<<dim3((N2 + 255) / 256), dim3(256), 0, stream>>>(offs, bsum, N2, 2 * E);
  k_binit<<<dim3((NB + 255) / 256), dim3(256), 0, stream>>>(offs, bcur, NB);
  k_bin<<<dim3(nbin), dim3(256), 0, stream>>>(ei1, et1, ei2, et2, bcur, staged, N, E, NB);
  k_scatter2<<<dim3(NB), dim3(256), 0, stream>>>(staged, offs, csr, N2);

  for (int g = 0; g < 2; ++g) {
    const float* x = g ? x2 : x1;
    const float* bv = g ? b2 : b1;
    float* outp = (float*)d_out + (size_t)g * N * 128;
    k_gemm_xt<<<dim3((N + 63) / 64, R), dim3(256), 0, stream>>>(
        x, Wb + (size_t)g * KK * 4096, xt, N);
    k_aggregate<<<dim3((N + 3) / 4), dim3(256), 0, stream>>>(
        csr, offs, sq, sk, xt, bv, outp, N, g * N);
  }
}

// Round 7
// 394.185 us; speedup vs baseline: 2.0740x; 1.1546x over previous
//
#include <hip/hip_runtime.h>

// RGATConv x2 (N=50000, E=800000, IN=HID=128, R=8) for MI355X/gfx950.
//
// Round-7: kill the node-level global histogram (49.8MB atomic write-amp,
// 68us). Bucket-level CSR build only at global scope:
//   k_count:       per-block LDS hist of 256-node buckets -> <=NB global
//                  atomics/block (153k total vs 1.6M).
//   k_bucket_scan: scan NB bucket totals -> bbase/bcur; offs[N2]=2E.
//   k_bin:         counting-sort chunks into bucket runs of `staged`.
//   k_scatter2:    per bucket: LDS node hist + scan -> writes offs[] slice
//                  AND final csr (stores confined to 16KB window).
// k_gemm_xt / k_aggregate unchanged from round-6.

typedef unsigned short u16;
typedef __attribute__((ext_vector_type(8))) short short8;
typedef __attribute__((ext_vector_type(4))) float floatx4;
typedef __attribute__((ext_vector_type(4))) float float4v;

__device__ __forceinline__ u16 f2bf(float f) {
  union { float f; unsigned u; } v; v.f = f;
  unsigned r = v.u + 0x7FFFu + ((v.u >> 16) & 1u);  // RNE
  return (u16)(r >> 16);
}
__device__ __forceinline__ float bflo(unsigned v) {
  union { unsigned u; float f; } c; c.u = v << 16; return c.f;
}
__device__ __forceinline__ float bfhi(unsigned v) {
  union { unsigned u; float f; } c; c.u = v & 0xffff0000u; return c.f;
}

// ---- 1. pack stacked W into B-fragment order (per graph) --------------------
__global__ void k_prep_wb(const float* __restrict__ W1, const float* __restrict__ W2,
                          u16* __restrict__ Wb, int KK) {
  int t = blockIdx.x * 256 + threadIdx.x;
  int lane = t & 63, nt = (t >> 6) & 7, kk = t >> 9;
  if (kk >= KK) return;
  const float* W = blockIdx.y ? W2 : W1;
  u16* out = Wb + (size_t)blockIdx.y * KK * 4096;
  int q = lane >> 4, m16 = lane & 15;
  int c = nt * 16 + m16;
  short8 v;
#pragma unroll
  for (int j = 0; j < 8; ++j) {
    int k = kk * 32 + q * 8 + j;
    v[j] = (short)f2bf(W[(size_t)k * 128 + c]);
  }
  *(short8*)(out + (size_t)t * 8) = v;
}

// ---- 2. Wq[g][r][d] = sum_c W[r][d][c]*q[c]; Wk likewise --------------------
__global__ void k_prep_wqk(const float* __restrict__ W1, const float* __restrict__ q1,
                           const float* __restrict__ k1, const float* __restrict__ W2,
                           const float* __restrict__ q2, const float* __restrict__ k2,
                           float* __restrict__ Wq, float* __restrict__ Wk, int RD) {
  int wid = (blockIdx.x * 256 + threadIdx.x) >> 6;
  int lane = threadIdx.x & 63;
  if (wid >= 2 * RD) return;
  int g = wid >= RD;
  const float* W = g ? W2 : W1;
  const float* qv = g ? q2 : q1;
  const float* kv = g ? k2 : k1;
  const float* row = W + (size_t)(wid - g * RD) * 128;
  float a0 = row[lane], a1 = row[lane + 64];
  float vq = a0 * qv[lane] + a1 * qv[lane + 64];
  float vk = a0 * kv[lane] + a1 * kv[lane + 64];
#pragma unroll
  for (int off = 32; off; off >>= 1) {
    vq += __shfl_xor(vq, off);
    vk += __shfl_xor(vk, off);
  }
  if (lane == 0) { Wq[wid] = vq; Wk[wid] = vk; }
}

// ---- 3. Bqk[g][kk][lane][j]: B-fragment of [Wq|Wk] (16 cols) ----------------
__global__ void k_prep_bqk(const float* __restrict__ Wq, const float* __restrict__ Wk,
                           u16* __restrict__ Bqk, int R) {
  int total = 2 * 4 * 64 * 8;
  for (int idx = threadIdx.x; idx < total; idx += 256) {
    int j = idx & 7, lane = (idx >> 3) & 63, kk = (idx >> 9) & 3, g = idx >> 11;
    int k = kk * 32 + ((lane >> 4) & 3) * 8 + j;
    int n = lane & 15;
    float v = (n < 8) ? Wq[(g * R + n) * 128 + k] : Wk[(g * R + (n & 7)) * 128 + k];
    Bqk[idx] = f2bf(v);
  }
}

// ---- 4. [sq|sk] = x @ [Wq|Wk] via MFMA --------------------------------------
__global__ void __launch_bounds__(256) k_sqk(
    const float* __restrict__ x1, const float* __restrict__ x2,
    const u16* __restrict__ Bqk, float* __restrict__ sq, float* __restrict__ sk,
    int N) {
  __shared__ u16 st[64 * 136];
  int g = blockIdx.y;
  const float* x = g ? x2 : x1;
  int row0 = blockIdx.x * 64;
  int t = threadIdx.x;
#pragma unroll
  for (int i = 0; i < 8; ++i) {
    int e = t * 4 + i * 1024;
    int rl = e >> 7, col = e & 127;
    int srow = row0 + rl; if (srow >= N) srow = N - 1;
    float4v v = *(const float4v*)(x + (size_t)srow * 128 + col);
    union { u16 h[4]; unsigned long long u; } pk;
    pk.h[0] = f2bf(v.x); pk.h[1] = f2bf(v.y);
    pk.h[2] = f2bf(v.z); pk.h[3] = f2bf(v.w);
    *(unsigned long long*)(st + rl * 136 + col) = pk.u;
  }
  __syncthreads();
  int wave = t >> 6, lane = t & 63;
  int q = lane >> 4, m16 = lane & 15;
  floatx4 acc = (floatx4){0.f, 0.f, 0.f, 0.f};
#pragma unroll
  for (int kk = 0; kk < 4; ++kk) {
    short8 a = *(const short8*)(st + (wave * 16 + m16) * 136 + kk * 32 + q * 8);
    short8 b = *(const short8*)(Bqk + ((size_t)g * 4 + kk) * 512 + lane * 8);
    acc = __builtin_amdgcn_mfma_f32_16x16x32_bf16(a, b, acc, 0, 0, 0);
  }
#pragma unroll
  for (int reg = 0; reg < 4; ++reg) {
    int node = row0 + wave * 16 + q * 4 + reg;
    if (node < N) {
      int gn = g * N + node;
      if (m16 < 8) sq[gn * 8 + m16] = acc[reg];
      else sk[gn * 8 + (m16 & 7)] = acc[reg];
    }
  }
}

// ---- 5a. bucket-level counts (LDS hist per block) ---------------------------
__global__ void __launch_bounds__(256) k_count(
    const int* __restrict__ d1, const int* __restrict__ d2,
    int* __restrict__ gcnt, int N, int E, int NB) {
  __shared__ int h[512];
  int tid = threadIdx.x;
  for (int i = tid; i < NB; i += 256) h[i] = 0;
  __syncthreads();
  int E2 = 2 * E;
  int e0 = blockIdx.x * 4096;
#pragma unroll
  for (int j = 0; j < 16; ++j) {
    int e = e0 + j * 256 + tid;
    if (e < E2) {
      int g = e >= E;
      int d = g ? d2[e - E] : d1[e];
      atomicAdd(&h[(g * N + d) >> 8], 1);
    }
  }
  __syncthreads();
  for (int i = tid; i < NB; i += 256)
    if (h[i]) atomicAdd(&gcnt[i], h[i]);
}

// ---- 5b. scan bucket totals -> bbase/bcur; offs[N2]=total -------------------
__global__ void k_bucket_scan(const int* __restrict__ gcnt, int* __restrict__ bbase,
                              int* __restrict__ bcur, int* __restrict__ offs,
                              int NB, int total, int N2) {
  __shared__ int sd[512];
  int tid = threadIdx.x;
  int v0 = (tid < NB) ? gcnt[tid] : 0;
  int v1 = (tid + 256 < NB) ? gcnt[tid + 256] : 0;
  sd[tid] = v0; sd[tid + 256] = v1;
  __syncthreads();
  for (int off = 1; off < 512; off <<= 1) {
    int t0 = (tid >= off) ? sd[tid - off] : 0;
    int t1 = (tid + 256 >= off) ? sd[tid + 256 - off] : 0;
    __syncthreads();
    sd[tid] += t0; sd[tid + 256] += t1;
    __syncthreads();
  }
  if (tid < NB) { int b = sd[tid] - v0; bbase[tid] = b; bcur[tid] = b; }
  if (tid + 256 < NB) { int b = sd[tid + 256] - v1; bbase[tid + 256] = b; bcur[tid + 256] = b; }
  if (tid == 0) { bbase[NB] = total; offs[N2] = total; }
}

// ---- 5c. bin edges into 256-node buckets (counting-sort per 4096-edge chunk)
__global__ void __launch_bounds__(256) k_bin(
    const int* __restrict__ ei1, const int* __restrict__ et1,
    const int* __restrict__ ei2, const int* __restrict__ et2,
    int* __restrict__ bcur, uint2* __restrict__ staged, int N, int E, int NB) {
  __shared__ int hist[512];
  __shared__ int basev[512];
  __shared__ int runstart[512];
  __shared__ unsigned sta[4096 * 2];  // 32 KB staging (dstg, srcet)
  int tid = threadIdx.x;
  int E2 = 2 * E;
  int e0 = blockIdx.x * 4096;
  int cnt2 = min(4096, E2 - e0);
  for (int i = tid; i < 512; i += 256) hist[i] = 0;
  __syncthreads();
  int dstg[16], srcet[16], rank[16];
#pragma unroll
  for (int j = 0; j < 16; ++j) {
    int e = e0 + j * 256 + tid;
    dstg[j] = -1;
    if (e < E2) {
      int g = e >= E;
      int el = e - (g ? E : 0);
      const int* ei = g ? ei2 : ei1;
      int s = ei[el], d = ei[E + el];
      int etv = (g ? et2 : et1)[el];
      dstg[j] = g * N + d;
      srcet[j] = (s << 3) | etv;
      rank[j] = atomicAdd(&hist[dstg[j] >> 8], 1);
    }
  }
  __syncthreads();
  basev[tid] = hist[tid];
  basev[tid + 256] = hist[tid + 256];
  __syncthreads();
  for (int off = 1; off < 512; off <<= 1) {
    int i0 = tid, i1 = tid + 256;
    int v0 = (i0 >= off) ? basev[i0 - off] : 0;
    int v1 = (i1 >= off) ? basev[i1 - off] : 0;
    __syncthreads();
    basev[i0] += v0; basev[i1] += v1;
    __syncthreads();
  }
  for (int i = tid; i < NB; i += 256)
    if (hist[i] > 0) runstart[i] = atomicAdd(&bcur[i], hist[i]);
  __syncthreads();
#pragma unroll
  for (int j = 0; j < 16; ++j)
    if (dstg[j] >= 0) {
      int b = dstg[j] >> 8;
      int slot = basev[b] - hist[b] + rank[j];
      sta[slot * 2] = (unsigned)dstg[j];
      sta[slot * 2 + 1] = (unsigned)srcet[j];
    }
  __syncthreads();
  for (int i = tid; i < cnt2; i += 256) {
    unsigned dg = sta[i * 2], se = sta[i * 2 + 1];
    int b = (int)(dg >> 8);
    int dest = runstart[b] + (i - (basev[b] - hist[b]));
    staged[dest] = make_uint2(dg, se);
  }
}

// ---- 5d. per-bucket: node-level offs + final sorted csr ---------------------
__global__ void __launch_bounds__(256) k_scatter2(
    const uint2* __restrict__ staged, const int* __restrict__ bbase,
    int* __restrict__ offs, int* __restrict__ csr, int N2) {
  __shared__ int hist[256];
  __shared__ int sd[256];
  __shared__ int cur[256];
  int b = blockIdx.x, tid = threadIdx.x;
  int nb0 = b << 8;
  int nnode = min(256, N2 - nb0);
  int s0 = bbase[b], s1 = bbase[b + 1];
  hist[tid] = 0;
  __syncthreads();
  for (int i = s0 + tid; i < s1; i += 256)
    atomicAdd(&hist[(int)staged[i].x - nb0], 1);
  __syncthreads();
  int v = hist[tid];
  sd[tid] = v; __syncthreads();
  for (int off = 1; off < 256; off <<= 1) {
    int t = (tid >= off) ? sd[tid - off] : 0;
    __syncthreads();
    sd[tid] += t;
    __syncthreads();
  }
  int ex = sd[tid] - v;  // exclusive scan
  if (tid < nnode) offs[nb0 + tid] = s0 + ex;
  cur[tid] = ex;
  __syncthreads();
  for (int i = s0 + tid; i < s1; i += 256) {
    uint2 en = staged[i];
    int node = (int)en.x - nb0;
    int sl = atomicAdd(&cur[node], 1);
    csr[s0 + sl] = (int)en.y;
  }
}

// ---- 6a. xt[r][n][c] = x_n @ W_r (MFMA, in-register fp32->bf16 A) -----------
__global__ void __launch_bounds__(256) k_gemm_xt(const float* __restrict__ x,
                                                 const u16* __restrict__ Wb,
                                                 u16* __restrict__ xt, int N) {
  __shared__ u16 st[4][16 * 136];
  int r = blockIdx.y;
  int wave = threadIdx.x >> 6, lane = threadIdx.x & 63;
  int m0 = blockIdx.x * 64 + wave * 16;
  int q = lane >> 4, m16 = lane & 15;
  int arow = m0 + m16; if (arow >= N) arow = N - 1;
  floatx4 acc[8];
#pragma unroll
  for (int nt = 0; nt < 8; ++nt) acc[nt] = (floatx4){0.f, 0.f, 0.f, 0.f};
#pragma unroll
  for (int kk = 0; kk < 4; ++kk) {
    const float* ap = x + (size_t)arow * 128 + kk * 32 + q * 8;
    float4v f0 = *(const float4v*)ap;
    float4v f1 = *(const float4v*)(ap + 4);
    short8 a;
    a[0] = (short)f2bf(f0.x); a[1] = (short)f2bf(f0.y);
    a[2] = (short)f2bf(f0.z); a[3] = (short)f2bf(f0.w);
    a[4] = (short)f2bf(f1.x); a[5] = (short)f2bf(f1.y);
    a[6] = (short)f2bf(f1.z); a[7] = (short)f2bf(f1.w);
    const u16* wbp = Wb + ((size_t)((r * 4 + kk) * 8) * 64 + lane) * 8;
#pragma unroll
    for (int nt = 0; nt < 8; ++nt) {
      short8 b = *(const short8*)(wbp + nt * 512);
      acc[nt] = __builtin_amdgcn_mfma_f32_16x16x32_bf16(a, b, acc[nt], 0, 0, 0);
    }
  }
  u16* s = st[wave];
#pragma unroll
  for (int nt = 0; nt < 8; ++nt) {
#pragma unroll
    for (int reg = 0; reg < 4; ++reg) {
      s[(q * 4 + reg) * 136 + nt * 16 + m16] = f2bf(acc[nt][reg]);
    }
  }
  __syncthreads();
#pragma unroll
  for (int m = 0; m < 16; ++m) {
    int gm = m0 + m;
    if (gm < N) {
      unsigned vv = *(const unsigned*)(s + m * 136 + lane * 2);
      *(unsigned*)(xt + ((size_t)r * N + gm) * 128 + lane * 2) = vv;
    }
  }
}

// ---- 6b. per-dst softmax + gather: one wave per node ------------------------
__global__ void __launch_bounds__(256) k_aggregate(
    const int* __restrict__ csr, const int* __restrict__ offs,
    const float* __restrict__ sq, const float* __restrict__ sk,
    const u16* __restrict__ xt, const float* __restrict__ bias,
    float* __restrict__ out, int N, int node_base) {
  int nl = blockIdx.x * 4 + (threadIdx.x >> 6);
  int lane = threadIdx.x & 63;
  if (nl >= N) return;
  int node = node_base + nl;
  int start = offs[node], end = offs[node + 1];
  const float* sqn = sq + (size_t)node * 8;

  float al[8]; int pl[8];
  float m = -INFINITY;
  {
    int c = 0;
    for (int i = start + lane; i < end; i += 64, ++c) {
      int p = csr[i]; int s = p >> 3, e = p & 7;
      float a = sqn[e] + sk[(size_t)(node_base + s) * 8 + e];
      a = (a > 0.f) ? a : 0.2f * a;
      if (c < 8) { al[c] = a; pl[c] = p; }
      m = fmaxf(m, a);
    }
  }
#pragma unroll
  for (int off = 32; off; off >>= 1) m = fmaxf(m, __shfl_xor(m, off));

  float ssum = 0.f;
  {
    int c = 0;
    for (int i = start + lane; i < end; i += 64, ++c) {
      float a;
      if (c < 8) a = al[c];
      else {
        int p = csr[i]; int s = p >> 3, e = p & 7;
        a = sqn[e] + sk[(size_t)(node_base + s) * 8 + e];
        a = (a > 0.f) ? a : 0.2f * a;
      }
      ssum += __expf(a - m);
    }
  }
#pragma unroll
  for (int off = 32; off; off >>= 1) ssum += __shfl_xor(ssum, off);
  float inv = 1.f / (ssum + 1e-16f);

  float acc0 = 0.f, acc1 = 0.f;
  const char* xtb = (const char*)xt;
  int c = 0;
  for (int base = start; base < end; base += 64, ++c) {
    int cnt = min(64, end - base);
    float w = 0.f; int b = 0;
    {
      int i = base + lane;
      if (i < end) {
        int p; float a;
        if (c < 8) { p = pl[c]; a = al[c]; }
        else {
          p = csr[i]; int s = p >> 3, e = p & 7;
          a = sqn[e] + sk[(size_t)(node_base + s) * 8 + e];
          a = (a > 0.f) ? a : 0.2f * a;
        }
        w = __expf(a - m) * inv;
        b = ((p & 7) * N + (p >> 3)) << 8;  // xt row base in BYTES
      }
    }
    int j = 0;
    for (; j + 3 < cnt; j += 4) {
      float w0 = __shfl(w, j), w1 = __shfl(w, j + 1),
            w2 = __shfl(w, j + 2), w3 = __shfl(w, j + 3);
      int b0 = __shfl(b, j), b1 = __shfl(b, j + 1),
          b2 = __shfl(b, j + 2), b3 = __shfl(b, j + 3);
      unsigned v0 = *(const unsigned*)(xtb + b0 + lane * 4);
      unsigned v1 = *(const unsigned*)(xtb + b1 + lane * 4);
      unsigned v2 = *(const unsigned*)(xtb + b2 + lane * 4);
      unsigned v3 = *(const unsigned*)(xtb + b3 + lane * 4);
      acc0 += w0 * bflo(v0); acc1 += w0 * bfhi(v0);
      acc0 += w1 * bflo(v1); acc1 += w1 * bfhi(v1);
      acc0 += w2 * bflo(v2); acc1 += w2 * bfhi(v2);
      acc0 += w3 * bflo(v3); acc1 += w3 * bfhi(v3);
    }
    for (; j < cnt; ++j) {
      float w0 = __shfl(w, j);
      int b0 = __shfl(b, j);
      unsigned v0 = *(const unsigned*)(xtb + b0 + lane * 4);
      acc0 += w0 * bflo(v0); acc1 += w0 * bfhi(v0);
    }
  }
  float o0 = fmaxf(acc0 + bias[lane * 2], 0.f);
  float o1 = fmaxf(acc1 + bias[lane * 2 + 1], 0.f);
  union { float f[2]; unsigned long long u; } pk;
  pk.f[0] = o0; pk.f[1] = o1;
  __builtin_nontemporal_store(pk.u,
      (unsigned long long*)(out + (size_t)nl * 128 + lane * 2));
}

// -----------------------------------------------------------------------------
extern "C" void kernel_launch(void* const* d_in, const int* in_sizes, int n_in,
                              void* d_out, int out_size, void* d_ws, size_t ws_size,
                              hipStream_t stream) {
  const float* x1 = (const float*)d_in[0];
  const int* ei1 = (const int*)d_in[1];
  const int* et1 = (const int*)d_in[2];
  const float* x2 = (const float*)d_in[3];
  const int* ei2 = (const int*)d_in[4];
  const int* et2 = (const int*)d_in[5];
  const float* W1 = (const float*)d_in[6];
  const float* q1 = (const float*)d_in[7];
  const float* k1 = (const float*)d_in[8];
  const float* b1 = (const float*)d_in[9];
  const float* W2 = (const float*)d_in[10];
  const float* q2 = (const float*)d_in[11];
  const float* k2 = (const float*)d_in[12];
  const float* b2 = (const float*)d_in[13];

  const int N = in_sizes[0] / 128;
  const int E = in_sizes[1] / 2;
  const int R = in_sizes[6] / (128 * 128);
  const int KK = R * 4;
  const int N2 = 2 * N;
  const int NB = (N2 + 255) >> 8;           // 256-node buckets (<=512)

  size_t off = 0;
  char* w = (char*)d_ws;
  auto carve = [&](size_t bytes) -> void* {
    void* p = w + off;
    off += (bytes + 255) & ~(size_t)255;
    return p;
  };
  u16* xt = (u16*)carve((size_t)R * N * 128 * 2);       // per-graph, reused
  uint2* staged = (uint2*)xt;                           // ALIAS: dead before gemm_xt
  u16* Wb = (u16*)carve((size_t)2 * KK * 4096 * 2);
  u16* Bqk = (u16*)carve((size_t)2 * 4 * 64 * 8 * 2);
  float* Wq = (float*)carve((size_t)2 * R * 128 * 4);
  float* Wk = (float*)carve((size_t)2 * R * 128 * 4);
  float* sq = (float*)carve((size_t)N2 * 8 * 4);
  float* sk = (float*)carve((size_t)N2 * 8 * 4);
  int* offs = (int*)carve((size_t)(N2 + 1) * 4);
  int* gcnt = (int*)carve(512 * 4);
  int* bbase = (int*)carve(520 * 4);
  int* bcur = (int*)carve(512 * 4);
  int* csr = (int*)carve((size_t)2 * E * 4);
  if (off > ws_size) return;

  const int nbin = (2 * E + 4095) / 4096;

  hipMemsetAsync(gcnt, 0, 512 * 4, stream);
  k_prep_wb<<<dim3((KK * 512 + 255) / 256, 2), dim3(256), 0, stream>>>(W1, W2, Wb, KK);
  k_prep_wqk<<<dim3((2 * R * 128 * 64 + 255) / 256), dim3(256), 0, stream>>>(
      W1, q1, k1, W2, q2, k2, Wq, Wk, R * 128);
  k_prep_bqk<<<dim3(1), dim3(256), 0, stream>>>(Wq, Wk, Bqk, R);
  k_sqk<<<dim3((N + 63) / 64, 2), dim3(256), 0, stream>>>(x1, x2, Bqk, sq, sk, N);
  k_count<<<dim3(nbin), dim3(256), 0, stream>>>(ei1 + E, ei2 + E, gcnt, N, E, NB);
  k_bucket_scan<<<dim3(1), dim3(256), 0, stream>>>(gcnt, bbase, bcur, offs, NB, 2 * E, N2);
  k_bin<<<dim3(nbin), dim3(256), 0, stream>>>(ei1, et1, ei2, et2, bcur, staged, N, E, NB);
  k_scatter2<<<dim3(NB), dim3(256), 0, stream>>>(staged, bbase, offs, csr, N2);

  for (int g = 0; g < 2; ++g) {
    const float* x = g ? x2 : x1;
    const float* bv = g ? b2 : b1;
    float* outp = (float*)d_out + (size_t)g * N * 128;
    k_gemm_xt<<<dim3((N + 63) / 64, R), dim3(256), 0, stream>>>(
        x, Wb + (size_t)g * KK * 4096, xt, N);
    k_aggregate<<<dim3((N + 3) / 4), dim3(256), 0, stream>>>(
        csr, offs, sq, sk, xt, bv, outp, N, g * N);
  }
}

// Round 8
// 366.945 us; speedup vs baseline: 2.2279x; 1.0742x over previous
//
#include <hip/hip_runtime.h>

// RGATConv x2 (N=50000, E=800000, IN=HID=128, R=8) for MI355X/gfx950.
//
// Round-8: k_gemm_xt restructured — grid loses the R dimension; each block
// loads its 64 x-rows ONCE (A-fragments in registers), loops over the 8
// relations {8 MFMAs -> LDS transpose -> dwordx4 stores}. Kills the 8x
// re-read of x (FETCH 101MB -> ~27MB) and quadruples store width.
// Rest identical to round-7.

typedef unsigned short u16;
typedef __attribute__((ext_vector_type(8))) short short8;
typedef __attribute__((ext_vector_type(4))) float floatx4;
typedef __attribute__((ext_vector_type(4))) float float4v;
typedef __attribute__((ext_vector_type(4))) unsigned uint4v;

__device__ __forceinline__ u16 f2bf(float f) {
  union { float f; unsigned u; } v; v.f = f;
  unsigned r = v.u + 0x7FFFu + ((v.u >> 16) & 1u);  // RNE
  return (u16)(r >> 16);
}
__device__ __forceinline__ float bflo(unsigned v) {
  union { unsigned u; float f; } c; c.u = v << 16; return c.f;
}
__device__ __forceinline__ float bfhi(unsigned v) {
  union { unsigned u; float f; } c; c.u = v & 0xffff0000u; return c.f;
}

// ---- 1. pack stacked W into B-fragment order (per graph) --------------------
__global__ void k_prep_wb(const float* __restrict__ W1, const float* __restrict__ W2,
                          u16* __restrict__ Wb, int KK) {
  int t = blockIdx.x * 256 + threadIdx.x;
  int lane = t & 63, nt = (t >> 6) & 7, kk = t >> 9;
  if (kk >= KK) return;
  const float* W = blockIdx.y ? W2 : W1;
  u16* out = Wb + (size_t)blockIdx.y * KK * 4096;
  int q = lane >> 4, m16 = lane & 15;
  int c = nt * 16 + m16;
  short8 v;
#pragma unroll
  for (int j = 0; j < 8; ++j) {
    int k = kk * 32 + q * 8 + j;
    v[j] = (short)f2bf(W[(size_t)k * 128 + c]);
  }
  *(short8*)(out + (size_t)t * 8) = v;
}

// ---- 2. Wq[g][r][d] = sum_c W[r][d][c]*q[c]; Wk likewise --------------------
__global__ void k_prep_wqk(const float* __restrict__ W1, const float* __restrict__ q1,
                           const float* __restrict__ k1, const float* __restrict__ W2,
                           const float* __restrict__ q2, const float* __restrict__ k2,
                           float* __restrict__ Wq, float* __restrict__ Wk, int RD) {
  int wid = (blockIdx.x * 256 + threadIdx.x) >> 6;
  int lane = threadIdx.x & 63;
  if (wid >= 2 * RD) return;
  int g = wid >= RD;
  const float* W = g ? W2 : W1;
  const float* qv = g ? q2 : q1;
  const float* kv = g ? k2 : k1;
  const float* row = W + (size_t)(wid - g * RD) * 128;
  float a0 = row[lane], a1 = row[lane + 64];
  float vq = a0 * qv[lane] + a1 * qv[lane + 64];
  float vk = a0 * kv[lane] + a1 * kv[lane + 64];
#pragma unroll
  for (int off = 32; off; off >>= 1) {
    vq += __shfl_xor(vq, off);
    vk += __shfl_xor(vk, off);
  }
  if (lane == 0) { Wq[wid] = vq; Wk[wid] = vk; }
}

// ---- 3. Bqk[g][kk][lane][j]: B-fragment of [Wq|Wk] (16 cols) ----------------
__global__ void k_prep_bqk(const float* __restrict__ Wq, const float* __restrict__ Wk,
                           u16* __restrict__ Bqk, int R) {
  int total = 2 * 4 * 64 * 8;
  for (int idx = threadIdx.x; idx < total; idx += 256) {
    int j = idx & 7, lane = (idx >> 3) & 63, kk = (idx >> 9) & 3, g = idx >> 11;
    int k = kk * 32 + ((lane >> 4) & 3) * 8 + j;
    int n = lane & 15;
    float v = (n < 8) ? Wq[(g * R + n) * 128 + k] : Wk[(g * R + (n & 7)) * 128 + k];
    Bqk[idx] = f2bf(v);
  }
}

// ---- 4. [sq|sk] = x @ [Wq|Wk] via MFMA --------------------------------------
__global__ void __launch_bounds__(256) k_sqk(
    const float* __restrict__ x1, const float* __restrict__ x2,
    const u16* __restrict__ Bqk, float* __restrict__ sq, float* __restrict__ sk,
    int N) {
  __shared__ u16 st[64 * 136];
  int g = blockIdx.y;
  const float* x = g ? x2 : x1;
  int row0 = blockIdx.x * 64;
  int t = threadIdx.x;
#pragma unroll
  for (int i = 0; i < 8; ++i) {
    int e = t * 4 + i * 1024;
    int rl = e >> 7, col = e & 127;
    int srow = row0 + rl; if (srow >= N) srow = N - 1;
    float4v v = *(const float4v*)(x + (size_t)srow * 128 + col);
    union { u16 h[4]; unsigned long long u; } pk;
    pk.h[0] = f2bf(v.x); pk.h[1] = f2bf(v.y);
    pk.h[2] = f2bf(v.z); pk.h[3] = f2bf(v.w);
    *(unsigned long long*)(st + rl * 136 + col) = pk.u;
  }
  __syncthreads();
  int wave = t >> 6, lane = t & 63;
  int q = lane >> 4, m16 = lane & 15;
  floatx4 acc = (floatx4){0.f, 0.f, 0.f, 0.f};
#pragma unroll
  for (int kk = 0; kk < 4; ++kk) {
    short8 a = *(const short8*)(st + (wave * 16 + m16) * 136 + kk * 32 + q * 8);
    short8 b = *(const short8*)(Bqk + ((size_t)g * 4 + kk) * 512 + lane * 8);
    acc = __builtin_amdgcn_mfma_f32_16x16x32_bf16(a, b, acc, 0, 0, 0);
  }
#pragma unroll
  for (int reg = 0; reg < 4; ++reg) {
    int node = row0 + wave * 16 + q * 4 + reg;
    if (node < N) {
      int gn = g * N + node;
      if (m16 < 8) sq[gn * 8 + m16] = acc[reg];
      else sk[gn * 8 + (m16 & 7)] = acc[reg];
    }
  }
}

// ---- 5a. bucket-level counts (LDS hist per block) ---------------------------
__global__ void __launch_bounds__(256) k_count(
    const int* __restrict__ d1, const int* __restrict__ d2,
    int* __restrict__ gcnt, int N, int E, int NB) {
  __shared__ int h[512];
  int tid = threadIdx.x;
  for (int i = tid; i < NB; i += 256) h[i] = 0;
  __syncthreads();
  int E2 = 2 * E;
  int e0 = blockIdx.x * 4096;
#pragma unroll
  for (int j = 0; j < 16; ++j) {
    int e = e0 + j * 256 + tid;
    if (e < E2) {
      int g = e >= E;
      int d = g ? d2[e - E] : d1[e];
      atomicAdd(&h[(g * N + d) >> 8], 1);
    }
  }
  __syncthreads();
  for (int i = tid; i < NB; i += 256)
    if (h[i]) atomicAdd(&gcnt[i], h[i]);
}

// ---- 5b. scan bucket totals -> bbase/bcur; offs[N2]=total -------------------
__global__ void k_bucket_scan(const int* __restrict__ gcnt, int* __restrict__ bbase,
                              int* __restrict__ bcur, int* __restrict__ offs,
                              int NB, int total, int N2) {
  __shared__ int sd[512];
  int tid = threadIdx.x;
  int v0 = (tid < NB) ? gcnt[tid] : 0;
  int v1 = (tid + 256 < NB) ? gcnt[tid + 256] : 0;
  sd[tid] = v0; sd[tid + 256] = v1;
  __syncthreads();
  for (int off = 1; off < 512; off <<= 1) {
    int t0 = (tid >= off) ? sd[tid - off] : 0;
    int t1 = (tid + 256 >= off) ? sd[tid + 256 - off] : 0;
    __syncthreads();
    sd[tid] += t0; sd[tid + 256] += t1;
    __syncthreads();
  }
  if (tid < NB) { int b = sd[tid] - v0; bbase[tid] = b; bcur[tid] = b; }
  if (tid + 256 < NB) { int b = sd[tid + 256] - v1; bbase[tid + 256] = b; bcur[tid + 256] = b; }
  if (tid == 0) { bbase[NB] = total; offs[N2] = total; }
}

// ---- 5c. bin edges into 256-node buckets (counting-sort per 4096-edge chunk)
__global__ void __launch_bounds__(256) k_bin(
    const int* __restrict__ ei1, const int* __restrict__ et1,
    const int* __restrict__ ei2, const int* __restrict__ et2,
    int* __restrict__ bcur, uint2* __restrict__ staged, int N, int E, int NB) {
  __shared__ int hist[512];
  __shared__ int basev[512];
  __shared__ int runstart[512];
  __shared__ unsigned sta[4096 * 2];  // 32 KB staging (dstg, srcet)
  int tid = threadIdx.x;
  int E2 = 2 * E;
  int e0 = blockIdx.x * 4096;
  int cnt2 = min(4096, E2 - e0);
  for (int i = tid; i < 512; i += 256) hist[i] = 0;
  __syncthreads();
  int dstg[16], srcet[16], rank[16];
#pragma unroll
  for (int j = 0; j < 16; ++j) {
    int e = e0 + j * 256 + tid;
    dstg[j] = -1;
    if (e < E2) {
      int g = e >= E;
      int el = e - (g ? E : 0);
      const int* ei = g ? ei2 : ei1;
      int s = ei[el], d = ei[E + el];
      int etv = (g ? et2 : et1)[el];
      dstg[j] = g * N + d;
      srcet[j] = (s << 3) | etv;
      rank[j] = atomicAdd(&hist[dstg[j] >> 8], 1);
    }
  }
  __syncthreads();
  basev[tid] = hist[tid];
  basev[tid + 256] = hist[tid + 256];
  __syncthreads();
  for (int off = 1; off < 512; off <<= 1) {
    int i0 = tid, i1 = tid + 256;
    int v0 = (i0 >= off) ? basev[i0 - off] : 0;
    int v1 = (i1 >= off) ? basev[i1 - off] : 0;
    __syncthreads();
    basev[i0] += v0; basev[i1] += v1;
    __syncthreads();
  }
  for (int i = tid; i < NB; i += 256)
    if (hist[i] > 0) runstart[i] = atomicAdd(&bcur[i], hist[i]);
  __syncthreads();
#pragma unroll
  for (int j = 0; j < 16; ++j)
    if (dstg[j] >= 0) {
      int b = dstg[j] >> 8;
      int slot = basev[b] - hist[b] + rank[j];
      sta[slot * 2] = (unsigned)dstg[j];
      sta[slot * 2 + 1] = (unsigned)srcet[j];
    }
  __syncthreads();
  for (int i = tid; i < cnt2; i += 256) {
    unsigned dg = sta[i * 2], se = sta[i * 2 + 1];
    int b = (int)(dg >> 8);
    int dest = runstart[b] + (i - (basev[b] - hist[b]));
    staged[dest] = make_uint2(dg, se);
  }
}

// ---- 5d. per-bucket: node-level offs + final sorted csr ---------------------
__global__ void __launch_bounds__(256) k_scatter2(
    const uint2* __restrict__ staged, const int* __restrict__ bbase,
    int* __restrict__ offs, int* __restrict__ csr, int N2) {
  __shared__ int hist[256];
  __shared__ int sd[256];
  __shared__ int cur[256];
  int b = blockIdx.x, tid = threadIdx.x;
  int nb0 = b << 8;
  int nnode = min(256, N2 - nb0);
  int s0 = bbase[b], s1 = bbase[b + 1];
  hist[tid] = 0;
  __syncthreads();
  for (int i = s0 + tid; i < s1; i += 256)
    atomicAdd(&hist[(int)staged[i].x - nb0], 1);
  __syncthreads();
  int v = hist[tid];
  sd[tid] = v; __syncthreads();
  for (int off = 1; off < 256; off <<= 1) {
    int t = (tid >= off) ? sd[tid - off] : 0;
    __syncthreads();
    sd[tid] += t;
    __syncthreads();
  }
  int ex = sd[tid] - v;  // exclusive scan
  if (tid < nnode) offs[nb0 + tid] = s0 + ex;
  cur[tid] = ex;
  __syncthreads();
  for (int i = s0 + tid; i < s1; i += 256) {
    uint2 en = staged[i];
    int node = (int)en.x - nb0;
    int sl = atomicAdd(&cur[node], 1);
    csr[s0 + sl] = (int)en.y;
  }
}

// ---- 6a. xt[r][n][c] = x_n @ W_r: A loaded once, loop over relations --------
__global__ void __launch_bounds__(256) k_gemm_xt(const float* __restrict__ x,
                                                 const u16* __restrict__ Wb,
                                                 u16* __restrict__ xt,
                                                 int N, int R) {
  __shared__ u16 st[4][16 * 136];
  int wave = threadIdx.x >> 6, lane = threadIdx.x & 63;
  int m0 = blockIdx.x * 64 + wave * 16;
  int q = lane >> 4, m16 = lane & 15;
  int arow = m0 + m16; if (arow >= N) arow = N - 1;
  // A fragments (16 rows x K=128), fp32 -> bf16 in-register, loaded ONCE
  short8 afrag[4];
#pragma unroll
  for (int kk = 0; kk < 4; ++kk) {
    const float* ap = x + (size_t)arow * 128 + kk * 32 + q * 8;
    float4v f0 = *(const float4v*)ap;
    float4v f1 = *(const float4v*)(ap + 4);
    short8 a;
    a[0] = (short)f2bf(f0.x); a[1] = (short)f2bf(f0.y);
    a[2] = (short)f2bf(f0.z); a[3] = (short)f2bf(f0.w);
    a[4] = (short)f2bf(f1.x); a[5] = (short)f2bf(f1.y);
    a[6] = (short)f2bf(f1.z); a[7] = (short)f2bf(f1.w);
    afrag[kk] = a;
  }
  u16* s = st[wave];
  int colq = lane & 15;
  int mrow = lane >> 4;
  for (int r = 0; r < R; ++r) {
    floatx4 acc[8];
#pragma unroll
    for (int nt = 0; nt < 8; ++nt) acc[nt] = (floatx4){0.f, 0.f, 0.f, 0.f};
#pragma unroll
    for (int kk = 0; kk < 4; ++kk) {
      const u16* wbp = Wb + ((size_t)((r * 4 + kk) * 8) * 64 + lane) * 8;
#pragma unroll
      for (int nt = 0; nt < 8; ++nt) {
        short8 b = *(const short8*)(wbp + nt * 512);
        acc[nt] = __builtin_amdgcn_mfma_f32_16x16x32_bf16(afrag[kk], b, acc[nt], 0, 0, 0);
      }
    }
    // C/D layout: col = nt*16 + m16, local row = q*4 + reg -> LDS transpose
#pragma unroll
    for (int nt = 0; nt < 8; ++nt) {
#pragma unroll
      for (int reg = 0; reg < 4; ++reg) {
        s[(q * 4 + reg) * 136 + nt * 16 + m16] = f2bf(acc[nt][reg]);
      }
    }
    __syncthreads();
    // dwordx4 stores: 4 iters x {4 rows, 16 lanes/row x 16B}
#pragma unroll
    for (int it = 0; it < 4; ++it) {
      int m = it * 4 + mrow;
      int gm = m0 + m;
      if (gm < N) {
        uint4v vv = *(const uint4v*)(s + m * 136 + colq * 8);
        *(uint4v*)(xt + ((size_t)r * N + gm) * 128 + colq * 8) = vv;
      }
    }
    __syncthreads();
  }
}

// ---- 6b. per-dst softmax + gather: one wave per node ------------------------
__global__ void __launch_bounds__(256) k_aggregate(
    const int* __restrict__ csr, const int* __restrict__ offs,
    const float* __restrict__ sq, const float* __restrict__ sk,
    const u16* __restrict__ xt, const float* __restrict__ bias,
    float* __restrict__ out, int N, int node_base) {
  int nl = blockIdx.x * 4 + (threadIdx.x >> 6);
  int lane = threadIdx.x & 63;
  if (nl >= N) return;
  int node = node_base + nl;
  int start = offs[node], end = offs[node + 1];
  const float* sqn = sq + (size_t)node * 8;

  float al[8]; int pl[8];
  float m = -INFINITY;
  {
    int c = 0;
    for (int i = start + lane; i < end; i += 64, ++c) {
      int p = csr[i]; int s = p >> 3, e = p & 7;
      float a = sqn[e] + sk[(size_t)(node_base + s) * 8 + e];
      a = (a > 0.f) ? a : 0.2f * a;
      if (c < 8) { al[c] = a; pl[c] = p; }
      m = fmaxf(m, a);
    }
  }
#pragma unroll
  for (int off = 32; off; off >>= 1) m = fmaxf(m, __shfl_xor(m, off));

  float ssum = 0.f;
  {
    int c = 0;
    for (int i = start + lane; i < end; i += 64, ++c) {
      float a;
      if (c < 8) a = al[c];
      else {
        int p = csr[i]; int s = p >> 3, e = p & 7;
        a = sqn[e] + sk[(size_t)(node_base + s) * 8 + e];
        a = (a > 0.f) ? a : 0.2f * a;
      }
      ssum += __expf(a - m);
    }
  }
#pragma unroll
  for (int off = 32; off; off >>= 1) ssum += __shfl_xor(ssum, off);
  float inv = 1.f / (ssum + 1e-16f);

  float acc0 = 0.f, acc1 = 0.f;
  const char* xtb = (const char*)xt;
  int c = 0;
  for (int base = start; base < end; base += 64, ++c) {
    int cnt = min(64, end - base);
    float w = 0.f; int b = 0;
    {
      int i = base + lane;
      if (i < end) {
        int p; float a;
        if (c < 8) { p = pl[c]; a = al[c]; }
        else {
          p = csr[i]; int s = p >> 3, e = p & 7;
          a = sqn[e] + sk[(size_t)(node_base + s) * 8 + e];
          a = (a > 0.f) ? a : 0.2f * a;
        }
        w = __expf(a - m) * inv;
        b = ((p & 7) * N + (p >> 3)) << 8;  // xt row base in BYTES
      }
    }
    int j = 0;
    for (; j + 3 < cnt; j += 4) {
      float w0 = __shfl(w, j), w1 = __shfl(w, j + 1),
            w2 = __shfl(w, j + 2), w3 = __shfl(w, j + 3);
      int b0 = __shfl(b, j), b1 = __shfl(b, j + 1),
          b2 = __shfl(b, j + 2), b3 = __shfl(b, j + 3);
      unsigned v0 = *(const unsigned*)(xtb + b0 + lane * 4);
      unsigned v1 = *(const unsigned*)(xtb + b1 + lane * 4);
      unsigned v2 = *(const unsigned*)(xtb + b2 + lane * 4);
      unsigned v3 = *(const unsigned*)(xtb + b3 + lane * 4);
      acc0 += w0 * bflo(v0); acc1 += w0 * bfhi(v0);
      acc0 += w1 * bflo(v1); acc1 += w1 * bfhi(v1);
      acc0 += w2 * bflo(v2); acc1 += w2 * bfhi(v2);
      acc0 += w3 * bflo(v3); acc1 += w3 * bfhi(v3);
    }
    for (; j < cnt; ++j) {
      float w0 = __shfl(w, j);
      int b0 = __shfl(b, j);
      unsigned v0 = *(const unsigned*)(xtb + b0 + lane * 4);
      acc0 += w0 * bflo(v0); acc1 += w0 * bfhi(v0);
    }
  }
  float o0 = fmaxf(acc0 + bias[lane * 2], 0.f);
  float o1 = fmaxf(acc1 + bias[lane * 2 + 1], 0.f);
  union { float f[2]; unsigned long long u; } pk;
  pk.f[0] = o0; pk.f[1] = o1;
  __builtin_nontemporal_store(pk.u,
      (unsigned long long*)(out + (size_t)nl * 128 + lane * 2));
}

// -----------------------------------------------------------------------------
extern "C" void kernel_launch(void* const* d_in, const int* in_sizes, int n_in,
                              void* d_out, int out_size, void* d_ws, size_t ws_size,
                              hipStream_t stream) {
  const float* x1 = (const float*)d_in[0];
  const int* ei1 = (const int*)d_in[1];
  const int* et1 = (const int*)d_in[2];
  const float* x2 = (const float*)d_in[3];
  const int* ei2 = (const int*)d_in[4];
  const int* et2 = (const int*)d_in[5];
  const float* W1 = (const float*)d_in[6];
  const float* q1 = (const float*)d_in[7];
  const float* k1 = (const float*)d_in[8];
  const float* b1 = (const float*)d_in[9];
  const float* W2 = (const float*)d_in[10];
  const float* q2 = (const float*)d_in[11];
  const float* k2 = (const float*)d_in[12];
  const float* b2 = (const float*)d_in[13];

  const int N = in_sizes[0] / 128;
  const int E = in_sizes[1] / 2;
  const int R = in_sizes[6] / (128 * 128);
  const int KK = R * 4;
  const int N2 = 2 * N;
  const int NB = (N2 + 255) >> 8;           // 256-node buckets (<=512)

  size_t off = 0;
  char* w = (char*)d_ws;
  auto carve = [&](size_t bytes) -> void* {
    void* p = w + off;
    off += (bytes + 255) & ~(size_t)255;
    return p;
  };
  u16* xt = (u16*)carve((size_t)R * N * 128 * 2);       // per-graph, reused
  uint2* staged = (uint2*)xt;                           // ALIAS: dead before gemm_xt
  u16* Wb = (u16*)carve((size_t)2 * KK * 4096 * 2);
  u16* Bqk = (u16*)carve((size_t)2 * 4 * 64 * 8 * 2);
  float* Wq = (float*)carve((size_t)2 * R * 128 * 4);
  float* Wk = (float*)carve((size_t)2 * R * 128 * 4);
  float* sq = (float*)carve((size_t)N2 * 8 * 4);
  float* sk = (float*)carve((size_t)N2 * 8 * 4);
  int* offs = (int*)carve((size_t)(N2 + 1) * 4);
  int* gcnt = (int*)carve(512 * 4);
  int* bbase = (int*)carve(520 * 4);
  int* bcur = (int*)carve(512 * 4);
  int* csr = (int*)carve((size_t)2 * E * 4);
  if (off > ws_size) return;

  const int nbin = (2 * E + 4095) / 4096;

  hipMemsetAsync(gcnt, 0, 512 * 4, stream);
  k_prep_wb<<<dim3((KK * 512 + 255) / 256, 2), dim3(256), 0, stream>>>(W1, W2, Wb, KK);
  k_prep_wqk<<<dim3((2 * R * 128 * 64 + 255) / 256), dim3(256), 0, stream>>>(
      W1, q1, k1, W2, q2, k2, Wq, Wk, R * 128);
  k_prep_bqk<<<dim3(1), dim3(256), 0, stream>>>(Wq, Wk, Bqk, R);
  k_sqk<<<dim3((N + 63) / 64, 2), dim3(256), 0, stream>>>(x1, x2, Bqk, sq, sk, N);
  k_count<<<dim3(nbin), dim3(256), 0, stream>>>(ei1 + E, ei2 + E, gcnt, N, E, NB);
  k_bucket_scan<<<dim3(1), dim3(256), 0, stream>>>(gcnt, bbase, bcur, offs, NB, 2 * E, N2);
  k_bin<<<dim3(nbin), dim3(256), 0, stream>>>(ei1, et1, ei2, et2, bcur, staged, N, E, NB);
  k_scatter2<<<dim3(NB), dim3(256), 0, stream>>>(staged, bbase, offs, csr, N2);

  for (int g = 0; g < 2; ++g) {
    const float* x = g ? x2 : x1;
    const float* bv = g ? b2 : b1;
    float* outp = (float*)d_out + (size_t)g * N * 128;
    k_gemm_xt<<<dim3((N + 63) / 64), dim3(256), 0, stream>>>(
        x, Wb + (size_t)g * KK * 4096, xt, N, R);
    k_aggregate<<<dim3((N + 3) / 4), dim3(256), 0, stream>>>(
        csr, offs, sq, sk, xt, bv, outp, N, g * N);
  }
}